// Round 7
// baseline (215.753 us; speedup 1.0000x reference)
//
#include <hip/hip_runtime.h>
#include <hip/hip_bf16.h>

// Problem constants
#define T_  4096
#define Bb  2
#define Nn  2048
#define Cc  768
#define Ee  24
#define Dd  64
#define Hh  12
#define KR  1568   // reduce GEMM K: 1536 (W_out) + 24 (b_out via dense gates) + 8 pad
#define KS  16     // gate k-split
#define KC  48     // 768 / KS
#define NB2 1024   // gate2 block count (T_/4)
#define SCL 0.18033688f   // 0.125 * log2(e) — folded into q at GEMM epilogue

typedef __attribute__((ext_vector_type(8))) short bf16x8;
typedef __attribute__((ext_vector_type(4))) short bf16x4;
typedef __attribute__((ext_vector_type(4))) float f32x4;

__device__ __forceinline__ unsigned short f2bf(float f) {
  union { float f; unsigned int i; } u; u.f = f;
  unsigned int r = u.i + 0x7FFFu + ((u.i >> 16) & 1u);
  return (unsigned short)(r >> 16);
}

__device__ __forceinline__ void gload16(const void* g, void* l) {
  __builtin_amdgcn_global_load_lds(
      (const __attribute__((address_space(1))) void*)g,
      (__attribute__((address_space(3))) void*)l, 16, 0, 0);
}

// ---------------------------------------------------------------------------
// Merged weight conversion (one dispatch): flat grid
//   blocks [0,288)          : W_in -> BqT   (e = i/12, c0 = (i%12)*64)
//   blocks [288, 288+588)   : [W_out;b_out] -> BrT (k0,n0)
//   blocks [876, 888)       : W_kv -> BkvT
// ---------------------------------------------------------------------------
__global__ __launch_bounds__(256) void convert_all_kernel(
    const float* __restrict__ W_in, const float* __restrict__ W_out,
    const float* __restrict__ b_out, const float* __restrict__ W_kv,
    unsigned short* __restrict__ BqT, unsigned short* __restrict__ BrT,
    unsigned short* __restrict__ BkvT)
{
  __shared__ float ls[64 * 129];
  const int bid = blockIdx.x, tid = threadIdx.x;
  if (bid < 288) {
    const int e = bid / 12, c0 = (bid % 12) * 64;
    #pragma unroll
    for (int i = 0; i < 16; ++i) {
      int L = tid + i * 256, c = L >> 6, d = L & 63;
      ls[c * 65 + d] = W_in[(size_t)e * Cc * Dd + (size_t)(c0 + c) * Dd + d];
    }
    __syncthreads();
    #pragma unroll
    for (int i = 0; i < 16; ++i) {
      int L = tid + i * 256, d = L >> 6, c = L & 63;
      BqT[(size_t)(e * Dd + d) * Cc + c0 + c] = f2bf(ls[c * 65 + d]);
    }
  } else if (bid < 876) {
    const int i2 = bid - 288;
    const int k0 = (i2 / 12) * 32, n0 = (i2 % 12) * 64;
    #pragma unroll
    for (int i = 0; i < 8; ++i) {
      int L = tid + i * 256, k = L >> 6, n = L & 63;
      int kk = k0 + k;
      float v = (kk < 1536) ? W_out[(size_t)kk * Cc + n0 + n]
              : (kk < 1560) ? b_out[(size_t)(kk - 1536) * Cc + n0 + n] : 0.f;
      ls[k * 65 + n] = v;
    }
    __syncthreads();
    #pragma unroll
    for (int i = 0; i < 8; ++i) {
      int L = tid + i * 256, n = L >> 5, k = L & 31;
      BrT[(size_t)(n0 + n) * KR + k0 + k] = f2bf(ls[k * 65 + n]);
    }
  } else {
    const int c0 = (bid - 876) * 64;
    #pragma unroll
    for (int i = 0; i < 32; ++i) {
      int L = tid + i * 256, c = L >> 7, j = L & 127;
      ls[c * 129 + j] = W_kv[(size_t)(c0 + c) * 128 + j];
    }
    __syncthreads();
    #pragma unroll
    for (int i = 0; i < 32; ++i) {
      int L = tid + i * 256, j = L >> 6, c = L & 63;
      BkvT[(size_t)j * Cc + c0 + c] = f2bf(ls[c * 129 + j]);
    }
  }
}

// ---------------------------------------------------------------------------
// bf16 MFMA GEMM (MODE1 only now): C = A @ BT^T (+bias).  Tile 64 x 64, BK=32.
// 2-phase double-buffered LDS (R5 config, best measured).
// Fused qall+kv.  BT = [BqT(1536) ; BkvT(128)] contiguous.
//   col < 1536 -> qallb (+b_in), PRE-SCALED by SCL
//   1536..1599 -> kbuf [B][N][D] (+b_kv lo)
//   1600..1663 -> vtbuf [B][D][N] (+b_kv hi), KEY-PERMUTED within each
//     64-key block: store position np for physical key p=nn&63 with
//     np = (p & 0x23) | (((p>>4)&1)<<2) | (((p>>2)&3)<<3)
//     -> a lane's S^T granules concatenate into valid K=32 PV B-frags.
// ---------------------------------------------------------------------------
__global__ __launch_bounds__(256) void gemm_qkv_kernel(
    const unsigned short* __restrict__ A, const unsigned short* __restrict__ BT,
    const float* __restrict__ bias, const float* __restrict__ bias2,
    unsigned short* __restrict__ Cout, unsigned short* __restrict__ Cout2,
    unsigned short* __restrict__ Cout3, int K)
{
  constexpr int BM = 64, BN = 64, MI = 2, NI = 2;
  __shared__ __align__(16) unsigned short As[2][BM * 32];
  __shared__ __align__(16) unsigned short Bs[2][BN * 32];
  const int tid = threadIdx.x, w = tid >> 6, lane = tid & 63;
  const int quad = lane >> 4, nl = lane & 15;
  const int m0 = blockIdx.x * BM, n0 = blockIdx.y * BN;
  const int mw = (w & 1) * 32, nw = (w >> 1) * 32;

  f32x4 acc[MI][NI];
  #pragma unroll
  for (int i = 0; i < MI; ++i)
    #pragma unroll
    for (int j = 0; j < NI; ++j) acc[i][j] = (f32x4){0.f, 0.f, 0.f, 0.f};

  const int rlane = lane >> 2, col8 = (lane & 3) * 8;
  const unsigned short* a0 = A + (size_t)(m0 + w * 16 + rlane) * K + col8;
  const unsigned short* b0 = BT + (size_t)(n0 + w * 16 + rlane) * K + col8;

  auto STAGE = [&](int bi, int k0) {
    gload16(a0 + k0, &As[bi][(w * 16) * 32]);
    gload16(b0 + k0, &Bs[bi][(w * 16) * 32]);
  };

  const int nt = K / 32;
  STAGE(0, 0);
  __syncthreads();
  for (int t = 0; t < nt; ++t) {
    const int cur = t & 1;
    if (t + 1 < nt) STAGE(cur ^ 1, (t + 1) * 32);   // issue next BEFORE compute

    const unsigned short* Ac = As[cur];
    const unsigned short* Bc = Bs[cur];
    bf16x8 af[MI], bfr[NI];
    #pragma unroll
    for (int mi = 0; mi < MI; ++mi)
      af[mi] = *(const bf16x8*)&Ac[(mw + mi * 16 + nl) * 32 + quad * 8];
    #pragma unroll
    for (int ni = 0; ni < NI; ++ni)
      bfr[ni] = *(const bf16x8*)&Bc[(nw + ni * 16 + nl) * 32 + quad * 8];
    #pragma unroll
    for (int mi = 0; mi < MI; ++mi)
      #pragma unroll
      for (int ni = 0; ni < NI; ++ni)
        acc[mi][ni] = __builtin_amdgcn_mfma_f32_16x16x32_bf16(
            af[mi], bfr[ni], acc[mi][ni], 0, 0, 0);

    __syncthreads();   // drain overlaps: loads had the compute phase to land
  }

  #pragma unroll
  for (int mi = 0; mi < MI; ++mi) {
    int rowb = m0 + mw + mi * 16 + quad * 4;
    int bb = rowb >> 11, nn = rowb & (Nn - 1);
    #pragma unroll
    for (int ni = 0; ni < NI; ++ni) {
      int col = n0 + nw + ni * 16 + nl;
      if (col < 1536) {
        float bv = bias[col];
        #pragma unroll
        for (int reg = 0; reg < 4; ++reg)
          Cout[(size_t)(rowb + reg) * 1536 + col] =
              f2bf((acc[mi][ni][reg] + bv) * SCL);
      } else {
        int c2 = col - 1536;
        float bv = bias2[c2];
        if (c2 < Dd) {
          #pragma unroll
          for (int reg = 0; reg < 4; ++reg)
            Cout2[((size_t)bb * Nn + nn + reg) * Dd + c2] =
                f2bf(acc[mi][ni][reg] + bv);
        } else {
          int p6 = nn & 63;
          int np = (nn & ~63) | (p6 & 0x23)
                 | (((p6 >> 4) & 1) << 2) | (((p6 >> 2) & 3) << 3);
          ushort4 v;
          v.x = f2bf(acc[mi][ni][0] + bv);
          v.y = f2bf(acc[mi][ni][1] + bv);
          v.z = f2bf(acc[mi][ni][2] + bv);
          v.w = f2bf(acc[mi][ni][3] + bv);
          *(ushort4*)(Cout3 + ((size_t)bb * Dd + (c2 - Dd)) * Nn + np) = v;
        }
      }
    }
  }
}

// ---------------------------------------------------------------------------
// FUSED reduce GEMM: out = combine(opart, gates) @ BrT^T, f32 out.
// Replaces scatter_kernel + old MODE0 GEMM: the A-matrix (old xeg) is
// computed ON THE FLY during staging — kills the 12.8 MB xeg write + 12.8 MB
// re-read + a full kernel launch, and reads only the SELECTED opart rows.
// Key property: each K-step's 32 cols lie inside ONE expert's 64-wide span
// (k0 % 32 == 0), so each A-row needs a single sel[e] lookup per K-step.
// Staging discipline (T14): global loads issued BEFORE the MFMA phase,
// dependent ds_write AFTER it, one __syncthreads per K-step.
// ---------------------------------------------------------------------------
__global__ __launch_bounds__(256) void gemm_reduce_kernel(
    const float* __restrict__ opart, const float* __restrict__ lpart,
    const int* __restrict__ idx, const float* __restrict__ gate,
    const unsigned short* __restrict__ BT, float* __restrict__ out)
{
  constexpr int BM = 64, BN = 64, MI = 2, NI = 2;
  __shared__ __align__(16) unsigned short As[2][BM * 32];
  __shared__ __align__(16) unsigned short Bs[2][BN * 32];
  __shared__ signed char sel8[64][Ee];   // expert -> head slot (-1 = unselected)
  __shared__ float glh_l[64][Hh];        // gate / l
  __shared__ float gg_l[64][Hh];         // raw gate

  const int tid = threadIdx.x, w = tid >> 6, lane = tid & 63;
  const int quad = lane >> 4, nl = lane & 15;
  const int m0 = blockIdx.x * BM, n0 = blockIdx.y * BN;
  const int mw = (w & 1) * 32, nw = (w >> 1) * 32;

  // ---- preamble: per-token selection tables ----
  for (int i = tid; i < 64 * Ee; i += 256) ((signed char*)sel8)[i] = -1;
  __syncthreads();
  for (int i = tid; i < 64 * Hh; i += 256) {
    int tl = i / Hh, hh = i - tl * Hh;
    int token = m0 + tl;
    int e = idx[token * Hh + hh];
    sel8[tl][e] = (signed char)hh;
    float g = gate[token * Hh + hh];
    gg_l[tl][hh] = g;
    int bb = token >> 11, nn = token & (Nn - 1);
    glh_l[tl][hh] = g / lpart[(size_t)(bb * Hh + hh) * Nn + nn];
  }

  f32x4 acc[MI][NI];
  #pragma unroll
  for (int i = 0; i < MI; ++i)
    #pragma unroll
    for (int j = 0; j < NI; ++j) acc[i][j] = (f32x4){0.f, 0.f, 0.f, 0.f};

  const int rlane = lane >> 2, col8 = (lane & 3) * 8;
  const int rl = w * 16 + rlane;                 // this lane's A row (token)
  const int token = m0 + rl;
  const int bb = token >> 11, nn = token & (Nn - 1);
  const unsigned short* b0 = BT + (size_t)(n0 + w * 16 + rlane) * KR + col8;

  // on-the-fly A fragment: 8 bf16 values for cols [k0+col8, k0+col8+8)
  auto MAKE_A = [&](int k0) -> bf16x8 {
    bf16x8 r = (bf16x8){0, 0, 0, 0, 0, 0, 0, 0};
    const int c0 = k0 + col8;
    if (c0 < 1536) {
      int e = c0 >> 6;
      int h = sel8[rl][e];
      if (h >= 0) {
        float sc = glh_l[rl][h];
        const float* op = opart +
            ((size_t)(bb * Hh + h) * Nn + nn) * Dd + (c0 & 63);
        float4 v0 = *(const float4*)op;
        float4 v1 = *(const float4*)(op + 4);
        union { __hip_bfloat162 h2[4]; bf16x8 v; } pk;
        pk.h2[0] = __float22bfloat162_rn(float2{sc * v0.x, sc * v0.y});
        pk.h2[1] = __float22bfloat162_rn(float2{sc * v0.z, sc * v0.w});
        pk.h2[2] = __float22bfloat162_rn(float2{sc * v1.x, sc * v1.y});
        pk.h2[3] = __float22bfloat162_rn(float2{sc * v1.z, sc * v1.w});
        r = pk.v;
      }
    } else {
      // dense-gate cols 1536..1559, zero pad 1560..1567 (runs once: k0=1536)
      #pragma unroll
      for (int j = 0; j < 8; ++j) {
        int c = c0 + j;
        if (c < 1560) {
          int h = sel8[rl][c - 1536];
          if (h >= 0) ((unsigned short*)&r)[j] = f2bf(gg_l[rl][h]);
        }
      }
    }
    return r;
  };

  const int nt = KR / 32;   // 49
  __syncthreads();          // tables ready
  bf16x8 a_first = MAKE_A(0);
  *(bf16x8*)&As[0][rl * 32 + col8] = a_first;
  gload16(b0, &Bs[0][(w * 16) * 32]);
  __syncthreads();

  for (int t = 0; t < nt; ++t) {
    const int cur = t & 1;
    bf16x8 an;
    if (t + 1 < nt) {
      an = MAKE_A((t + 1) * 32);                    // issue loads early
      gload16(b0 + (t + 1) * 32, &Bs[cur ^ 1][(w * 16) * 32]);
    }

    const unsigned short* Ac = As[cur];
    const unsigned short* Bc = Bs[cur];
    bf16x8 af[MI], bfr[NI];
    #pragma unroll
    for (int mi = 0; mi < MI; ++mi)
      af[mi] = *(const bf16x8*)&Ac[(mw + mi * 16 + nl) * 32 + quad * 8];
    #pragma unroll
    for (int ni = 0; ni < NI; ++ni)
      bfr[ni] = *(const bf16x8*)&Bc[(nw + ni * 16 + nl) * 32 + quad * 8];
    #pragma unroll
    for (int mi = 0; mi < MI; ++mi)
      #pragma unroll
      for (int ni = 0; ni < NI; ++ni)
        acc[mi][ni] = __builtin_amdgcn_mfma_f32_16x16x32_bf16(
            af[mi], bfr[ni], acc[mi][ni], 0, 0, 0);

    if (t + 1 < nt)
      *(bf16x8*)&As[cur ^ 1][rl * 32 + col8] = an;  // write late
    __syncthreads();
  }

  #pragma unroll
  for (int mi = 0; mi < MI; ++mi) {
    int rowb = m0 + mw + mi * 16 + quad * 4;
    #pragma unroll
    for (int ni = 0; ni < NI; ++ni) {
      int col = n0 + nw + ni * 16 + nl;
      #pragma unroll
      for (int reg = 0; reg < 4; ++reg)
        out[(size_t)(rowb + reg) * Cc + col] = acc[mi][ni][reg];
    }
  }
}

// ---------------------------------------------------------------------------
// gate1: partial logits + fused x->bf16 conversion
// ---------------------------------------------------------------------------
#define XPAD 52
__global__ __launch_bounds__(256) void gate1_kernel(
    const float* __restrict__ x, const float* __restrict__ wg,
    float* __restrict__ partial, unsigned short* __restrict__ xb)
{
  __shared__ __align__(16) float xs[256 * XPAD];
  __shared__ __align__(16) float wsT[Ee * KC];
  const int tid = threadIdx.x;
  const int t0 = blockIdx.x * 256;
  const int s = blockIdx.y, k0 = s * KC;

  #pragma unroll
  for (int i = 0; i < 12; ++i) {
    int f = tid + i * 256;
    int token = f / 12, j = f % 12;
    size_t gofs = (size_t)(t0 + token) * Cc + k0 + j * 4;
    float4 v = *(const float4*)&x[gofs];
    *(float4*)&xs[token * XPAD + j * 4] = v;
    ushort4 o;
    o.x = f2bf(v.x); o.y = f2bf(v.y); o.z = f2bf(v.z); o.w = f2bf(v.w);
    *(ushort4*)&xb[gofs] = o;
  }
  for (int i = tid; i < Ee * KC; i += 256)
    wsT[(i % Ee) * KC + i / Ee] = wg[k0 * Ee + i];
  __syncthreads();

  float xr[KC];
  #pragma unroll
  for (int kg = 0; kg < KC / 4; ++kg)
    *(float4*)&xr[kg * 4] = *(const float4*)&xs[tid * XPAD + kg * 4];

  float acc[Ee];
  #pragma unroll
  for (int e = 0; e < Ee; ++e) acc[e] = 0.f;
  #pragma unroll
  for (int e = 0; e < Ee; ++e) {
    #pragma unroll
    for (int kg = 0; kg < KC / 4; ++kg) {
      float4 wv = *(const float4*)&wsT[e * KC + kg * 4];
      acc[e] += xr[kg * 4 + 0] * wv.x + xr[kg * 4 + 1] * wv.y
              + xr[kg * 4 + 2] * wv.z + xr[kg * 4 + 3] * wv.w;
    }
  }

  float* dst = partial + ((size_t)(t0 + tid) * KS + s) * Ee;
  #pragma unroll
  for (int eg = 0; eg < Ee / 4; ++eg)
    *(float4*)&dst[eg * 4] = *(float4*)&acc[eg * 4];
}

// ---------------------------------------------------------------------------
// gate2: logits -> softmax -> top-12 -> gates; block stats -> bstats
// ---------------------------------------------------------------------------
__global__ __launch_bounds__(256) void gate2_kernel(
    const float* __restrict__ partial,
    int* __restrict__ idx, float* __restrict__ gate, float* __restrict__ bstats)
{
  __shared__ float xls[4][KS * Ee];
  __shared__ float sacc[49];
  const int tid = threadIdx.x;
  const int w = tid >> 6, lane = tid & 63;
  const int t = blockIdx.x * 4 + w;

  if (tid < 49) sacc[tid] = 0.f;

  const float* p = partial + (size_t)t * (KS * Ee);
  #pragma unroll
  for (int i = 0; i < 6; ++i) xls[w][lane + i * 64] = p[lane + i * 64];

  float logit = -1e30f;
  if (lane < Ee) {
    float acc = 0.f;
    #pragma unroll
    for (int s = 0; s < KS; ++s) acc += xls[w][s * Ee + lane];
    logit = acc;
  }
  float m = logit;
  for (int o = 32; o; o >>= 1) m = fmaxf(m, __shfl_xor(m, o));
  float pr = (lane < Ee) ? expf(logit - m) : 0.f;
  float s = pr;
  for (int o = 32; o; o >>= 1) s += __shfl_xor(s, o);
  float prob = pr / s;
  float lse = m + logf(s);

  bool sel = false;
  float my_p = 0.f; int my_e = -1;
  for (int h = 0; h < Hh; ++h) {
    float v = (lane < Ee && !sel) ? prob : -1.f;
    int ix = lane;
    for (int o = 32; o; o >>= 1) {
      float ov = __shfl_xor(v, o); int oi = __shfl_xor(ix, o);
      if (ov > v || (ov == v && oi < ix)) { v = ov; ix = oi; }
    }
    if (lane == ix) sel = true;
    if (lane == h) { my_p = v; my_e = ix; }
  }
  float gsum = (lane < Hh) ? my_p : 0.f;
  for (int o = 32; o; o >>= 1) gsum += __shfl_xor(gsum, o);
  if (lane < Hh) {
    idx[t * Hh + lane] = my_e;
    gate[t * Hh + lane] = my_p / (gsum + 1e-6f);
  }

  __syncthreads();
  if (lane < Ee) atomicAdd(&sacc[lane], prob);
  if (lane < Hh) atomicAdd(&sacc[24 + my_e], 1.0f);
  if (lane == 0) atomicAdd(&sacc[48], lse * lse);
  __syncthreads();
  if (tid < 49) bstats[(size_t)tid * NB2 + blockIdx.x] = sacc[tid];
}

// ---------------------------------------------------------------------------
// Flash attention (UNCHANGED from the 203us-best R5 config): transposed,
// 16 q/wave, in-register P, PV at K=32, 3-deep rotating LDS buffers (48 KB),
// 2-tile prefetch via global_load_lds, counted s_waitcnt vmcnt(8).
// Grid (N/64, B*H) = 768 blocks = 3 blocks/CU at 48 KB LDS.
// Six structural variants measured 40-47us — converged; do not touch.
// ---------------------------------------------------------------------------
__global__ __launch_bounds__(256, 3) void attn_kernel(
    const unsigned short* __restrict__ qallb, const int* __restrict__ idx,
    const unsigned short* __restrict__ kbuf, const unsigned short* __restrict__ vtbuf,
    float* __restrict__ opart, float* __restrict__ lpart)
{
  __shared__ __align__(16) unsigned short ksl[3][64 * 64];  // K tiles [key][d], swizzled
  __shared__ __align__(16) unsigned short vtl[3][64 * 64];  // V^T tiles [d][key-perm]

  const int tid = threadIdx.x;
  const int w = tid >> 6, lane = tid & 63;
  const int quad = lane >> 4, nl = lane & 15;
  const int bh = blockIdx.y;
  const int b = bh / Hh, h = bh - b * Hh;
  const int qw = blockIdx.x * 64 + w * 16;      // wave's 16 queries

  // Q B-frags (gathered via expert idx; pre-scaled by SCL at GEMM epilogue)
  const int tq = b * Nn + qw + nl;
  const int eq = idx[tq * Hh + h];
  const unsigned short* qrow = qallb + (size_t)tq * (Ee * Dd) + eq * Dd + quad * 8;
  const bf16x8 qB0 = *(const bf16x8*)(qrow);
  const bf16x8 qB1 = *(const bf16x8*)(qrow + 32);

  f32x4 acc[4];
  #pragma unroll
  for (int dg = 0; dg < 4; ++dg) acc[dg] = (f32x4){0.f, 0.f, 0.f, 0.f};
  float l = 0.f;

  const int sr  = lane >> 3;
  const int cbd = (lane & 7) ^ sr;              // XOR-swizzled source chunk
  const int xl  = nl & 7;
  const int ca0 = (quad ^ xl) * 8;              // b128 chunk offsets (K and V)
  const int ca1 = ((quad + 4) ^ xl) * 8;

  // wave-level staging bases (each wave stages rows w*16..w*16+15 of a tile)
  const unsigned short* kgbase =
      kbuf + ((size_t)b * Nn + w * 16 + sr) * Dd + cbd * 8;
  const unsigned short* vgbase =
      vtbuf + ((size_t)b * Dd + w * 16 + sr) * Nn + cbd * 8;

  auto STAGE = [&](int bi, int t) {
    const int j0 = t * 64;
    #pragma unroll
    for (int i = 0; i < 2; ++i) {
      gload16(kgbase + (size_t)(j0 + i * 8) * Dd, &ksl[bi][(w * 16 + i * 8) * 64]);
      gload16(vgbase + (size_t)(i * 8) * Nn + j0, &vtl[bi][(w * 16 + i * 8) * 64]);
    }
  };

  auto COMPUTE = [&](const unsigned short* ks_, const unsigned short* vt_) {
    __builtin_amdgcn_s_setprio(1);
    // --- S^T = K·Q^T ---
    bf16x4 pf[4];
    #pragma unroll
    for (int kg = 0; kg < 4; ++kg) {
      const unsigned short* kr = ks_ + (kg * 16 + nl) * 64;
      bf16x8 a0 = *(const bf16x8*)(kr + ca0);
      bf16x8 a1 = *(const bf16x8*)(kr + ca1);
      f32x4 c = {0.f, 0.f, 0.f, 0.f};
      c = __builtin_amdgcn_mfma_f32_16x16x32_bf16(a0, qB0, c, 0, 0, 0);
      c = __builtin_amdgcn_mfma_f32_16x16x32_bf16(a1, qB1, c, 0, 0, 0);
      float p0 = __builtin_amdgcn_exp2f(c[0]);
      float p1 = __builtin_amdgcn_exp2f(c[1]);
      float p2 = __builtin_amdgcn_exp2f(c[2]);
      float p3 = __builtin_amdgcn_exp2f(c[3]);
      l += (p0 + p1) + (p2 + p3);
      union { __hip_bfloat162 h2[2]; bf16x4 v; } pk;
      pk.h2[0] = __float22bfloat162_rn(float2{p0, p1});
      pk.h2[1] = __float22bfloat162_rn(float2{p2, p3});
      pf[kg] = pk.v;
    }
    bf16x8 pb0 = __builtin_shufflevector(pf[0], pf[1], 0, 1, 2, 3, 4, 5, 6, 7);
    bf16x8 pb1 = __builtin_shufflevector(pf[2], pf[3], 0, 1, 2, 3, 4, 5, 6, 7);
    // --- O^T += V^T·P^T at K=32 ---
    #pragma unroll
    for (int dg = 0; dg < 4; ++dg) {
      const unsigned short* vrow = vt_ + (dg * 16 + nl) * 64;
      bf16x8 v0 = *(const bf16x8*)(vrow + ca0);
      bf16x8 v1 = *(const bf16x8*)(vrow + ca1);
      acc[dg] = __builtin_amdgcn_mfma_f32_16x16x32_bf16(v0, pb0, acc[dg], 0, 0, 0);
      acc[dg] = __builtin_amdgcn_mfma_f32_16x16x32_bf16(v1, pb1, acc[dg], 0, 0, 0);
    }
    __builtin_amdgcn_s_setprio(0);
  };

  // ---- software pipeline: 32 tiles, 2-deep prefetch, 3 rotating buffers ----
  STAGE(0, 0);
  STAGE(1, 1);
  #pragma unroll 1
  for (int t = 0; t < 30; t += 3) {
    STAGE(2, t + 2);
    asm volatile("s_waitcnt vmcnt(8)" ::: "memory");
    __builtin_amdgcn_s_barrier();
    __builtin_amdgcn_sched_barrier(0);
    COMPUTE(ksl[0], vtl[0]);
    __builtin_amdgcn_sched_barrier(0);
    asm volatile("" ::: "memory");
    __builtin_amdgcn_s_barrier();

    STAGE(0, t + 3);
    asm volatile("s_waitcnt vmcnt(8)" ::: "memory");
    __builtin_amdgcn_s_barrier();
    __builtin_amdgcn_sched_barrier(0);
    COMPUTE(ksl[1], vtl[1]);
    __builtin_amdgcn_sched_barrier(0);
    asm volatile("" ::: "memory");
    __builtin_amdgcn_s_barrier();

    STAGE(1, t + 4);
    asm volatile("s_waitcnt vmcnt(8)" ::: "memory");
    __builtin_amdgcn_s_barrier();
    __builtin_amdgcn_sched_barrier(0);
    COMPUTE(ksl[2], vtl[2]);
    __builtin_amdgcn_sched_barrier(0);
    asm volatile("" ::: "memory");
    __builtin_amdgcn_s_barrier();
  }
  asm volatile("s_waitcnt vmcnt(4)" ::: "memory");
  __builtin_amdgcn_s_barrier();
  __builtin_amdgcn_sched_barrier(0);
  COMPUTE(ksl[0], vtl[0]);
  __builtin_amdgcn_sched_barrier(0);
  asm volatile("s_waitcnt vmcnt(0)" ::: "memory");
  __builtin_amdgcn_s_barrier();
  __builtin_amdgcn_sched_barrier(0);
  COMPUTE(ksl[1], vtl[1]);

  float lg = l;
  lg += __shfl_xor(lg, 16);
  lg += __shfl_xor(lg, 32);
  if (lane < 16)
    lpart[(size_t)bh * Nn + qw + nl] = lg;
  float* orow = opart + ((size_t)bh * Nn + qw + nl) * Dd + quad * 4;
  #pragma unroll
  for (int dg = 0; dg < 4; ++dg) {
    float4 o;
    o.x = acc[dg][0]; o.y = acc[dg][1];
    o.z = acc[dg][2]; o.w = acc[dg][3];
    *(float4*)(orow + dg * 16) = o;
  }
}

// ---------------------------------------------------------------------------
// aux1: parallel bstats row-sum -> stats2[49];  aux2: finalize
// ---------------------------------------------------------------------------
__global__ __launch_bounds__(256) void aux1_kernel(
    const float* __restrict__ bstats, float* __restrict__ stats2)
{
  __shared__ float r[4];
  const int j = blockIdx.x, tid = threadIdx.x;
  float4 v = *(const float4*)&bstats[(size_t)j * NB2 + tid * 4];
  float s = (v.x + v.y) + (v.z + v.w);
  for (int o = 32; o; o >>= 1) s += __shfl_xor(s, o);
  if ((tid & 63) == 0) r[tid >> 6] = s;
  __syncthreads();
  if (tid == 0) stats2[j] = (r[0] + r[1]) + (r[2] + r[3]);
}

__global__ void aux2_kernel(const float* __restrict__ stats2,
                            float* __restrict__ out, int out_size)
{
  const int lane = threadIdx.x;
  float a = (lane < Ee) ? stats2[lane] : 0.f;
  float b = (lane < Ee) ? stats2[24 + lane] : 0.f;
  float pt = a, ft = b, sw = a * b;
  for (int o = 32; o; o >>= 1) {
    pt += __shfl_xor(pt, o); ft += __shfl_xor(ft, o); sw += __shfl_xor(sw, o);
  }
  if (lane == 0) {
    float sswitch = (float)Ee * sw / (pt * ft);
    float z = stats2[48] * (1.0f / (float)T_);
    out[out_size - 1] = 0.1f * sswitch + 0.001f * z;
  }
}

// ---------------------------------------------------------------------------
extern "C" void kernel_launch(void* const* d_in, const int* in_sizes, int n_in,
                              void* d_out, int out_size, void* d_ws, size_t ws_size,
                              hipStream_t stream)
{
  const float* x     = (const float*)d_in[0];
  const float* wg    = (const float*)d_in[1];
  const float* W_in  = (const float*)d_in[2];
  const float* b_in  = (const float*)d_in[3];
  const float* W_out = (const float*)d_in[4];
  const float* b_out = (const float*)d_in[5];
  const float* W_kv  = (const float*)d_in[6];
  const float* b_kv  = (const float*)d_in[7];
  float* out = (float*)d_out;

  char* ws = (char*)d_ws;
  size_t off = 0;
  auto carve = [&](size_t bytes) -> void* {
    void* p = ws + off;
    off = (off + bytes + 255) & ~(size_t)255;
    return p;
  };
  int*            idx    = (int*)           carve((size_t)T_ * Hh * 4);
  float*          gate   = (float*)         carve((size_t)T_ * Hh * 4);
  float*          bstats = (float*)         carve((size_t)49 * NB2 * 4);
  float*          stats2 = (float*)         carve(256);
  float*          lpart  = (float*)         carve((size_t)Bb * Hh * Nn * 4);
  float*          lgate  = (float*)         carve((size_t)T_ * KS * Ee * 4);
  unsigned short* xb     = (unsigned short*)carve((size_t)T_ * Cc * 2);
  unsigned short* BqkvT  = (unsigned short*)carve((size_t)(Ee * Dd + 128) * Cc * 2);
  unsigned short* BkvT   = BqkvT + (size_t)Ee * Dd * Cc;
  unsigned short* BrT    = (unsigned short*)carve((size_t)Cc * KR * 2);
  unsigned short* kbuf   = (unsigned short*)carve((size_t)T_ * Dd * 2);
  unsigned short* vtbuf  = (unsigned short*)carve((size_t)T_ * Dd * 2);
  unsigned short* qallb  = (unsigned short*)carve((size_t)T_ * Ee * Dd * 2);
  float*          opart  = (float*)         carve((size_t)Bb * Hh * Nn * Dd * 4);

  // merged weight conversions (one dispatch)
  convert_all_kernel<<<888, 256, 0, stream>>>(
      W_in, W_out, b_out, W_kv, BqkvT, BrT, BkvT);

  // gating (+ fused x -> bf16)
  gate1_kernel<<<dim3(T_ / 256, KS), 256, 0, stream>>>(x, wg, lgate, xb);
  gate2_kernel<<<NB2, 256, 0, stream>>>(lgate, idx, gate, bstats);

  // fused qall + kv GEMM: 64x64 tiles, grid (64, 26) = 1664 blocks
  gemm_qkv_kernel<<<dim3(T_ / 64, 26), 256, 0, stream>>>(
      xb, BqkvT, b_in, b_kv, qallb, kbuf, vtbuf, Cc);

  // attention: grid (32, 24) = 768 blocks (3/CU at 48 KB LDS), pipelined
  attn_kernel<<<dim3(Nn / 64, Bb * Hh), 256, 0, stream>>>(
      qallb, idx, kbuf, vtbuf, opart, lpart);

  // FUSED combine + reduce GEMM (scatter kernel + xeg buffer eliminated):
  // 64x64 tiles, grid (64, 12) = 768 blocks
  gemm_reduce_kernel<<<dim3(T_ / 64, Cc / 64), 256, 0, stream>>>(
      opart, lpart, idx, gate, BrT, out);

  // aux loss
  aux1_kernel<<<49, 256, 0, stream>>>(bstats, stats2);
  aux2_kernel<<<1, 64, 0, stream>>>(stats2, out, out_size);
}

// Round 8
// 211.285 us; speedup vs baseline: 1.0211x; 1.0211x over previous
//
#include <hip/hip_runtime.h>
#include <hip/hip_bf16.h>

// Problem constants
#define T_  4096
#define Bb  2
#define Nn  2048
#define Cc  768
#define Ee  24
#define Dd  64
#define Hh  12
#define KR  1568   // reduce GEMM K: 1536 (W_out) + 24 (b_out via dense gates) + 8 pad
#define KS  16     // gate k-split
#define KC  48     // 768 / KS
#define NB2 1024   // gate2 block count (T_/4)
#define SCL 0.18033688f   // 0.125 * log2(e) — folded into q at GEMM epilogue

typedef __attribute__((ext_vector_type(8))) short bf16x8;
typedef __attribute__((ext_vector_type(4))) short bf16x4;
typedef __attribute__((ext_vector_type(4))) float f32x4;

__device__ __forceinline__ unsigned short f2bf(float f) {
  union { float f; unsigned int i; } u; u.f = f;
  unsigned int r = u.i + 0x7FFFu + ((u.i >> 16) & 1u);
  return (unsigned short)(r >> 16);
}

__device__ __forceinline__ void gload16(const void* g, void* l) {
  __builtin_amdgcn_global_load_lds(
      (const __attribute__((address_space(1))) void*)g,
      (__attribute__((address_space(3))) void*)l, 16, 0, 0);
}

// ---------------------------------------------------------------------------
// Merged weight conversion (one dispatch): flat grid
//   blocks [0,288)          : W_in -> BqT   (e = i/12, c0 = (i%12)*64)
//   blocks [288, 288+588)   : [W_out;b_out] -> BrT (k0,n0)
//   blocks [876, 888)       : W_kv -> BkvT
// ---------------------------------------------------------------------------
__global__ __launch_bounds__(256) void convert_all_kernel(
    const float* __restrict__ W_in, const float* __restrict__ W_out,
    const float* __restrict__ b_out, const float* __restrict__ W_kv,
    unsigned short* __restrict__ BqT, unsigned short* __restrict__ BrT,
    unsigned short* __restrict__ BkvT)
{
  __shared__ float ls[64 * 129];
  const int bid = blockIdx.x, tid = threadIdx.x;
  if (bid < 288) {
    const int e = bid / 12, c0 = (bid % 12) * 64;
    #pragma unroll
    for (int i = 0; i < 16; ++i) {
      int L = tid + i * 256, c = L >> 6, d = L & 63;
      ls[c * 65 + d] = W_in[(size_t)e * Cc * Dd + (size_t)(c0 + c) * Dd + d];
    }
    __syncthreads();
    #pragma unroll
    for (int i = 0; i < 16; ++i) {
      int L = tid + i * 256, d = L >> 6, c = L & 63;
      BqT[(size_t)(e * Dd + d) * Cc + c0 + c] = f2bf(ls[c * 65 + d]);
    }
  } else if (bid < 876) {
    const int i2 = bid - 288;
    const int k0 = (i2 / 12) * 32, n0 = (i2 % 12) * 64;
    #pragma unroll
    for (int i = 0; i < 8; ++i) {
      int L = tid + i * 256, k = L >> 6, n = L & 63;
      int kk = k0 + k;
      float v = (kk < 1536) ? W_out[(size_t)kk * Cc + n0 + n]
              : (kk < 1560) ? b_out[(size_t)(kk - 1536) * Cc + n0 + n] : 0.f;
      ls[k * 65 + n] = v;
    }
    __syncthreads();
    #pragma unroll
    for (int i = 0; i < 8; ++i) {
      int L = tid + i * 256, n = L >> 5, k = L & 31;
      BrT[(size_t)(n0 + n) * KR + k0 + k] = f2bf(ls[k * 65 + n]);
    }
  } else {
    const int c0 = (bid - 876) * 64;
    #pragma unroll
    for (int i = 0; i < 32; ++i) {
      int L = tid + i * 256, c = L >> 7, j = L & 127;
      ls[c * 129 + j] = W_kv[(size_t)(c0 + c) * 128 + j];
    }
    __syncthreads();
    #pragma unroll
    for (int i = 0; i < 32; ++i) {
      int L = tid + i * 256, j = L >> 6, c = L & 63;
      BkvT[(size_t)j * Cc + c0 + c] = f2bf(ls[c * 129 + j]);
    }
  }
}

// ---------------------------------------------------------------------------
// bf16 MFMA GEMM: C = A[M][K] @ BT[N][K]^T (+bias).  Tile 64 x BN, BK=32.
// 2-phase double-buffered LDS (R5 config, best measured).
// XCD-AWARE SWIZZLE (T1): 1D grid (nwg % 8 == 0), decoded n-FASTEST so each
// XCD's contiguous chunk covers ~8 m-panels x ALL n-tiles: every A-panel is
// read ONCE per XCD (was x26/x12 via L3) and B turns per-XCD-L2-resident.
// Traffic audit (64x64 tiles, linear grid): qkv 320 MB, reduce 300 MB logical
// -> L3-BW-bound ~10 TB/s explained the unaccounted ~55+ us.  With T1: ~30 MB.
// MODE 0: f32 out (reduce GEMM).
// MODE 1: fused qall+kv.  BT = [BqT(1536) ; BkvT(128)] contiguous.
//   col < 1536 -> qallb (+b_in), PRE-SCALED by SCL
//   1536..1599 -> kbuf [B][N][D] (+b_kv lo)
//   1600..1663 -> vtbuf [B][D][N] (+b_kv hi), KEY-PERMUTED within each
//     64-key block: store position np for physical key p=nn&63 with
//     np = (p & 0x23) | (((p>>4)&1)<<2) | (((p>>2)&3)<<3)
//     -> a lane's S^T granules concatenate into valid K=32 PV B-frags.
// ---------------------------------------------------------------------------
template<int MODE, int BN, int NT>
__global__ __launch_bounds__(256) void gemm_bt_kernel(
    const unsigned short* __restrict__ A, const unsigned short* __restrict__ BT,
    const float* __restrict__ bias, const float* __restrict__ bias2,
    void* __restrict__ Cout, void* __restrict__ Cout2, void* __restrict__ Cout3,
    int K, int ldc)
{
  constexpr int BM = 64;
  constexpr int MI = 2;            // 2 x 16 rows per wave
  constexpr int NI = BN / 32;      // 16-col frags per wave
  __shared__ __align__(16) unsigned short As[2][BM * 32];
  __shared__ __align__(16) unsigned short Bs[2][BN * 32];
  const int tid = threadIdx.x, w = tid >> 6, lane = tid & 63;
  const int quad = lane >> 4, nl = lane & 15;

  // T1 swizzle: bijective for gridDim.x % 8 == 0
  const int chunk = gridDim.x >> 3;
  const int swz = (blockIdx.x & 7) * chunk + (blockIdx.x >> 3);
  const int m0 = (swz / NT) * BM, n0 = (swz % NT) * BN;

  const int mw = (w & 1) * 32, nw = (w >> 1) * (BN / 2);

  f32x4 acc[MI][NI];
  #pragma unroll
  for (int i = 0; i < MI; ++i)
    #pragma unroll
    for (int j = 0; j < NI; ++j) acc[i][j] = (f32x4){0.f, 0.f, 0.f, 0.f};

  const int rlane = lane >> 2, col8 = (lane & 3) * 8;
  const unsigned short* a0 = A + (size_t)(m0 + w * 16 + rlane) * K + col8;
  const unsigned short* b0 =
      BT + (size_t)(n0 + (BN == 128 ? w * 32 : w * 16) + rlane) * K + col8;
  const unsigned short* b1 = b0 + (size_t)16 * K;

  auto STAGE = [&](int bi, int k0) {
    gload16(a0 + k0, &As[bi][(w * 16) * 32]);
    if (BN == 128) {
      gload16(b0 + k0, &Bs[bi][(w * 32) * 32]);
      gload16(b1 + k0, &Bs[bi][(w * 32 + 16) * 32]);
    } else {
      gload16(b0 + k0, &Bs[bi][(w * 16) * 32]);
    }
  };

  const int nt = K / 32;
  STAGE(0, 0);
  __syncthreads();
  for (int t = 0; t < nt; ++t) {
    const int cur = t & 1;
    if (t + 1 < nt) STAGE(cur ^ 1, (t + 1) * 32);   // issue next BEFORE compute

    const unsigned short* Ac = As[cur];
    const unsigned short* Bc = Bs[cur];
    bf16x8 af[MI], bfr[NI];
    #pragma unroll
    for (int mi = 0; mi < MI; ++mi)
      af[mi] = *(const bf16x8*)&Ac[(mw + mi * 16 + nl) * 32 + quad * 8];
    #pragma unroll
    for (int ni = 0; ni < NI; ++ni)
      bfr[ni] = *(const bf16x8*)&Bc[(nw + ni * 16 + nl) * 32 + quad * 8];
    #pragma unroll
    for (int mi = 0; mi < MI; ++mi)
      #pragma unroll
      for (int ni = 0; ni < NI; ++ni)
        acc[mi][ni] = __builtin_amdgcn_mfma_f32_16x16x32_bf16(
            af[mi], bfr[ni], acc[mi][ni], 0, 0, 0);

    __syncthreads();   // drain overlaps: loads had the compute phase to land
  }

  #pragma unroll
  for (int mi = 0; mi < MI; ++mi) {
    int rowb = m0 + mw + mi * 16 + quad * 4;
    int bb = rowb >> 11, nn = rowb & (Nn - 1);
    #pragma unroll
    for (int ni = 0; ni < NI; ++ni) {
      int col = n0 + nw + ni * 16 + nl;
      if (MODE == 0) {
        #pragma unroll
        for (int reg = 0; reg < 4; ++reg)
          ((float*)Cout)[(size_t)(rowb + reg) * ldc + col] = acc[mi][ni][reg];
      } else {
        if (col < 1536) {
          float bv = bias[col];
          #pragma unroll
          for (int reg = 0; reg < 4; ++reg)
            ((unsigned short*)Cout)[(size_t)(rowb + reg) * 1536 + col] =
                f2bf((acc[mi][ni][reg] + bv) * SCL);
        } else {
          int c2 = col - 1536;
          float bv = bias2[c2];
          if (c2 < Dd) {
            #pragma unroll
            for (int reg = 0; reg < 4; ++reg)
              ((unsigned short*)Cout2)[((size_t)bb * Nn + nn + reg) * Dd + c2] =
                  f2bf(acc[mi][ni][reg] + bv);
          } else {
            int p6 = nn & 63;
            int np = (nn & ~63) | (p6 & 0x23)
                   | (((p6 >> 4) & 1) << 2) | (((p6 >> 2) & 3) << 3);
            ushort4 v;
            v.x = f2bf(acc[mi][ni][0] + bv);
            v.y = f2bf(acc[mi][ni][1] + bv);
            v.z = f2bf(acc[mi][ni][2] + bv);
            v.w = f2bf(acc[mi][ni][3] + bv);
            *(ushort4*)((unsigned short*)Cout3 +
                        ((size_t)bb * Dd + (c2 - Dd)) * Nn + np) = v;
          }
        }
      }
    }
  }
}

// ---------------------------------------------------------------------------
// gate1: partial logits + fused x->bf16 conversion
// ---------------------------------------------------------------------------
#define XPAD 52
__global__ __launch_bounds__(256) void gate1_kernel(
    const float* __restrict__ x, const float* __restrict__ wg,
    float* __restrict__ partial, unsigned short* __restrict__ xb)
{
  __shared__ __align__(16) float xs[256 * XPAD];
  __shared__ __align__(16) float wsT[Ee * KC];
  const int tid = threadIdx.x;
  const int t0 = blockIdx.x * 256;
  const int s = blockIdx.y, k0 = s * KC;

  #pragma unroll
  for (int i = 0; i < 12; ++i) {
    int f = tid + i * 256;
    int token = f / 12, j = f % 12;
    size_t gofs = (size_t)(t0 + token) * Cc + k0 + j * 4;
    float4 v = *(const float4*)&x[gofs];
    *(float4*)&xs[token * XPAD + j * 4] = v;
    ushort4 o;
    o.x = f2bf(v.x); o.y = f2bf(v.y); o.z = f2bf(v.z); o.w = f2bf(v.w);
    *(ushort4*)&xb[gofs] = o;
  }
  for (int i = tid; i < Ee * KC; i += 256)
    wsT[(i % Ee) * KC + i / Ee] = wg[k0 * Ee + i];
  __syncthreads();

  float xr[KC];
  #pragma unroll
  for (int kg = 0; kg < KC / 4; ++kg)
    *(float4*)&xr[kg * 4] = *(const float4*)&xs[tid * XPAD + kg * 4];

  float acc[Ee];
  #pragma unroll
  for (int e = 0; e < Ee; ++e) acc[e] = 0.f;
  #pragma unroll
  for (int e = 0; e < Ee; ++e) {
    #pragma unroll
    for (int kg = 0; kg < KC / 4; ++kg) {
      float4 wv = *(const float4*)&wsT[e * KC + kg * 4];
      acc[e] += xr[kg * 4 + 0] * wv.x + xr[kg * 4 + 1] * wv.y
              + xr[kg * 4 + 2] * wv.z + xr[kg * 4 + 3] * wv.w;
    }
  }

  float* dst = partial + ((size_t)(t0 + tid) * KS + s) * Ee;
  #pragma unroll
  for (int eg = 0; eg < Ee / 4; ++eg)
    *(float4*)&dst[eg * 4] = *(float4*)&acc[eg * 4];
}

// ---------------------------------------------------------------------------
// gate2: logits -> softmax -> top-12 -> gates; block stats -> bstats
// ---------------------------------------------------------------------------
__global__ __launch_bounds__(256) void gate2_kernel(
    const float* __restrict__ partial,
    int* __restrict__ idx, float* __restrict__ gate, float* __restrict__ bstats)
{
  __shared__ float xls[4][KS * Ee];
  __shared__ float sacc[49];
  const int tid = threadIdx.x;
  const int w = tid >> 6, lane = tid & 63;
  const int t = blockIdx.x * 4 + w;

  if (tid < 49) sacc[tid] = 0.f;

  const float* p = partial + (size_t)t * (KS * Ee);
  #pragma unroll
  for (int i = 0; i < 6; ++i) xls[w][lane + i * 64] = p[lane + i * 64];

  float logit = -1e30f;
  if (lane < Ee) {
    float acc = 0.f;
    #pragma unroll
    for (int s = 0; s < KS; ++s) acc += xls[w][s * Ee + lane];
    logit = acc;
  }
  float m = logit;
  for (int o = 32; o; o >>= 1) m = fmaxf(m, __shfl_xor(m, o));
  float pr = (lane < Ee) ? expf(logit - m) : 0.f;
  float s = pr;
  for (int o = 32; o; o >>= 1) s += __shfl_xor(s, o);
  float prob = pr / s;
  float lse = m + logf(s);

  bool sel = false;
  float my_p = 0.f; int my_e = -1;
  for (int h = 0; h < Hh; ++h) {
    float v = (lane < Ee && !sel) ? prob : -1.f;
    int ix = lane;
    for (int o = 32; o; o >>= 1) {
      float ov = __shfl_xor(v, o); int oi = __shfl_xor(ix, o);
      if (ov > v || (ov == v && oi < ix)) { v = ov; ix = oi; }
    }
    if (lane == ix) sel = true;
    if (lane == h) { my_p = v; my_e = ix; }
  }
  float gsum = (lane < Hh) ? my_p : 0.f;
  for (int o = 32; o; o >>= 1) gsum += __shfl_xor(gsum, o);
  if (lane < Hh) {
    idx[t * Hh + lane] = my_e;
    gate[t * Hh + lane] = my_p / (gsum + 1e-6f);
  }

  __syncthreads();
  if (lane < Ee) atomicAdd(&sacc[lane], prob);
  if (lane < Hh) atomicAdd(&sacc[24 + my_e], 1.0f);
  if (lane == 0) atomicAdd(&sacc[48], lse * lse);
  __syncthreads();
  if (tid < 49) bstats[(size_t)tid * NB2 + blockIdx.x] = sacc[tid];
}

// ---------------------------------------------------------------------------
// Flash attention (UNCHANGED from the 203us-best R5 config): transposed,
// 16 q/wave, in-register P, PV at K=32, 3-deep rotating LDS buffers (48 KB),
// 2-tile prefetch via global_load_lds, counted s_waitcnt vmcnt(8).
// Grid (N/64, B*H) = 768 blocks = 3 blocks/CU at 48 KB LDS.
// Six structural variants measured 40-47us — converged; do not touch.
// ---------------------------------------------------------------------------
__global__ __launch_bounds__(256, 3) void attn_kernel(
    const unsigned short* __restrict__ qallb, const int* __restrict__ idx,
    const unsigned short* __restrict__ kbuf, const unsigned short* __restrict__ vtbuf,
    float* __restrict__ opart, float* __restrict__ lpart)
{
  __shared__ __align__(16) unsigned short ksl[3][64 * 64];  // K tiles [key][d], swizzled
  __shared__ __align__(16) unsigned short vtl[3][64 * 64];  // V^T tiles [d][key-perm]

  const int tid = threadIdx.x;
  const int w = tid >> 6, lane = tid & 63;
  const int quad = lane >> 4, nl = lane & 15;
  const int bh = blockIdx.y;
  const int b = bh / Hh, h = bh - b * Hh;
  const int qw = blockIdx.x * 64 + w * 16;      // wave's 16 queries

  // Q B-frags (gathered via expert idx; pre-scaled by SCL at GEMM epilogue)
  const int tq = b * Nn + qw + nl;
  const int eq = idx[tq * Hh + h];
  const unsigned short* qrow = qallb + (size_t)tq * (Ee * Dd) + eq * Dd + quad * 8;
  const bf16x8 qB0 = *(const bf16x8*)(qrow);
  const bf16x8 qB1 = *(const bf16x8*)(qrow + 32);

  f32x4 acc[4];
  #pragma unroll
  for (int dg = 0; dg < 4; ++dg) acc[dg] = (f32x4){0.f, 0.f, 0.f, 0.f};
  float l = 0.f;

  const int sr  = lane >> 3;
  const int cbd = (lane & 7) ^ sr;              // XOR-swizzled source chunk
  const int xl  = nl & 7;
  const int ca0 = (quad ^ xl) * 8;              // b128 chunk offsets (K and V)
  const int ca1 = ((quad + 4) ^ xl) * 8;

  // wave-level staging bases (each wave stages rows w*16..w*16+15 of a tile)
  const unsigned short* kgbase =
      kbuf + ((size_t)b * Nn + w * 16 + sr) * Dd + cbd * 8;
  const unsigned short* vgbase =
      vtbuf + ((size_t)b * Dd + w * 16 + sr) * Nn + cbd * 8;

  auto STAGE = [&](int bi, int t) {
    const int j0 = t * 64;
    #pragma unroll
    for (int i = 0; i < 2; ++i) {
      gload16(kgbase + (size_t)(j0 + i * 8) * Dd, &ksl[bi][(w * 16 + i * 8) * 64]);
      gload16(vgbase + (size_t)(i * 8) * Nn + j0, &vtl[bi][(w * 16 + i * 8) * 64]);
    }
  };

  auto COMPUTE = [&](const unsigned short* ks_, const unsigned short* vt_) {
    __builtin_amdgcn_s_setprio(1);
    // --- S^T = K·Q^T ---
    bf16x4 pf[4];
    #pragma unroll
    for (int kg = 0; kg < 4; ++kg) {
      const unsigned short* kr = ks_ + (kg * 16 + nl) * 64;
      bf16x8 a0 = *(const bf16x8*)(kr + ca0);
      bf16x8 a1 = *(const bf16x8*)(kr + ca1);
      f32x4 c = {0.f, 0.f, 0.f, 0.f};
      c = __builtin_amdgcn_mfma_f32_16x16x32_bf16(a0, qB0, c, 0, 0, 0);
      c = __builtin_amdgcn_mfma_f32_16x16x32_bf16(a1, qB1, c, 0, 0, 0);
      float p0 = __builtin_amdgcn_exp2f(c[0]);
      float p1 = __builtin_amdgcn_exp2f(c[1]);
      float p2 = __builtin_amdgcn_exp2f(c[2]);
      float p3 = __builtin_amdgcn_exp2f(c[3]);
      l += (p0 + p1) + (p2 + p3);
      union { __hip_bfloat162 h2[2]; bf16x4 v; } pk;
      pk.h2[0] = __float22bfloat162_rn(float2{p0, p1});
      pk.h2[1] = __float22bfloat162_rn(float2{p2, p3});
      pf[kg] = pk.v;
    }
    bf16x8 pb0 = __builtin_shufflevector(pf[0], pf[1], 0, 1, 2, 3, 4, 5, 6, 7);
    bf16x8 pb1 = __builtin_shufflevector(pf[2], pf[3], 0, 1, 2, 3, 4, 5, 6, 7);
    // --- O^T += V^T·P^T at K=32 ---
    #pragma unroll
    for (int dg = 0; dg < 4; ++dg) {
      const unsigned short* vrow = vt_ + (dg * 16 + nl) * 64;
      bf16x8 v0 = *(const bf16x8*)(vrow + ca0);
      bf16x8 v1 = *(const bf16x8*)(vrow + ca1);
      acc[dg] = __builtin_amdgcn_mfma_f32_16x16x32_bf16(v0, pb0, acc[dg], 0, 0, 0);
      acc[dg] = __builtin_amdgcn_mfma_f32_16x16x32_bf16(v1, pb1, acc[dg], 0, 0, 0);
    }
    __builtin_amdgcn_s_setprio(0);
  };

  // ---- software pipeline: 32 tiles, 2-deep prefetch, 3 rotating buffers ----
  STAGE(0, 0);
  STAGE(1, 1);
  #pragma unroll 1
  for (int t = 0; t < 30; t += 3) {
    STAGE(2, t + 2);
    asm volatile("s_waitcnt vmcnt(8)" ::: "memory");
    __builtin_amdgcn_s_barrier();
    __builtin_amdgcn_sched_barrier(0);
    COMPUTE(ksl[0], vtl[0]);
    __builtin_amdgcn_sched_barrier(0);
    asm volatile("" ::: "memory");
    __builtin_amdgcn_s_barrier();

    STAGE(0, t + 3);
    asm volatile("s_waitcnt vmcnt(8)" ::: "memory");
    __builtin_amdgcn_s_barrier();
    __builtin_amdgcn_sched_barrier(0);
    COMPUTE(ksl[1], vtl[1]);
    __builtin_amdgcn_sched_barrier(0);
    asm volatile("" ::: "memory");
    __builtin_amdgcn_s_barrier();

    STAGE(1, t + 4);
    asm volatile("s_waitcnt vmcnt(8)" ::: "memory");
    __builtin_amdgcn_s_barrier();
    __builtin_amdgcn_sched_barrier(0);
    COMPUTE(ksl[2], vtl[2]);
    __builtin_amdgcn_sched_barrier(0);
    asm volatile("" ::: "memory");
    __builtin_amdgcn_s_barrier();
  }
  asm volatile("s_waitcnt vmcnt(4)" ::: "memory");
  __builtin_amdgcn_s_barrier();
  __builtin_amdgcn_sched_barrier(0);
  COMPUTE(ksl[0], vtl[0]);
  __builtin_amdgcn_sched_barrier(0);
  asm volatile("s_waitcnt vmcnt(0)" ::: "memory");
  __builtin_amdgcn_s_barrier();
  __builtin_amdgcn_sched_barrier(0);
  COMPUTE(ksl[1], vtl[1]);

  float lg = l;
  lg += __shfl_xor(lg, 16);
  lg += __shfl_xor(lg, 32);
  if (lane < 16)
    lpart[(size_t)bh * Nn + qw + nl] = lg;
  float* orow = opart + ((size_t)bh * Nn + qw + nl) * Dd + quad * 4;
  #pragma unroll
  for (int dg = 0; dg < 4; ++dg) {
    float4 o;
    o.x = acc[dg][0]; o.y = acc[dg][1];
    o.z = acc[dg][2]; o.w = acc[dg][3];
    *(float4*)(orow + dg * 16) = o;
  }
}

// ---------------------------------------------------------------------------
// Scatter + combine: xeg row from opart/l with gate folded in.
// ---------------------------------------------------------------------------
__global__ __launch_bounds__(256) void scatter_kernel(
    const float* __restrict__ opart, const float* __restrict__ lpart,
    const int* __restrict__ idx, const float* __restrict__ gate,
    unsigned short* __restrict__ xeg)
{
  __shared__ int   sel[Ee];
  __shared__ float glh[Hh];   // gate / l
  __shared__ float gg[Hh];    // raw gate (for the dense-gate K-rows)
  const int t = blockIdx.x, b = t >> 11, nn = t & (Nn - 1);
  const int tid = threadIdx.x;
  if (tid < Ee) sel[tid] = -1;
  __syncthreads();
  if (tid < Hh) {
    int e = idx[t * Hh + tid];
    sel[e] = tid;
    float g = gate[t * Hh + tid];
    gg[tid] = g;
    size_t row = (size_t)(b * Hh + tid) * Nn + nn;
    glh[tid] = g / lpart[row];
  }
  __syncthreads();
  for (int c = tid; c < KR; c += 256) {
    float v = 0.f;
    if (c < 1536) {
      int e = c >> 6, h = sel[e];
      if (h >= 0) {
        size_t oofs = ((size_t)(b * Hh + h) * Nn + nn) * Dd + (c & 63);
        v = glh[h] * opart[oofs];
      }
    } else if (c < 1560) {
      int h = sel[c - 1536];
      if (h >= 0) v = gg[h];
    }
    xeg[(size_t)t * KR + c] = f2bf(v);
  }
}

// ---------------------------------------------------------------------------
// aux1: parallel bstats row-sum -> stats2[49];  aux2: finalize
// ---------------------------------------------------------------------------
__global__ __launch_bounds__(256) void aux1_kernel(
    const float* __restrict__ bstats, float* __restrict__ stats2)
{
  __shared__ float r[4];
  const int j = blockIdx.x, tid = threadIdx.x;
  float4 v = *(const float4*)&bstats[(size_t)j * NB2 + tid * 4];
  float s = (v.x + v.y) + (v.z + v.w);
  for (int o = 32; o; o >>= 1) s += __shfl_xor(s, o);
  if ((tid & 63) == 0) r[tid >> 6] = s;
  __syncthreads();
  if (tid == 0) stats2[j] = (r[0] + r[1]) + (r[2] + r[3]);
}

__global__ void aux2_kernel(const float* __restrict__ stats2,
                            float* __restrict__ out, int out_size)
{
  const int lane = threadIdx.x;
  float a = (lane < Ee) ? stats2[lane] : 0.f;
  float b = (lane < Ee) ? stats2[24 + lane] : 0.f;
  float pt = a, ft = b, sw = a * b;
  for (int o = 32; o; o >>= 1) {
    pt += __shfl_xor(pt, o); ft += __shfl_xor(ft, o); sw += __shfl_xor(sw, o);
  }
  if (lane == 0) {
    float sswitch = (float)Ee * sw / (pt * ft);
    float z = stats2[48] * (1.0f / (float)T_);
    out[out_size - 1] = 0.1f * sswitch + 0.001f * z;
  }
}

// ---------------------------------------------------------------------------
extern "C" void kernel_launch(void* const* d_in, const int* in_sizes, int n_in,
                              void* d_out, int out_size, void* d_ws, size_t ws_size,
                              hipStream_t stream)
{
  const float* x     = (const float*)d_in[0];
  const float* wg    = (const float*)d_in[1];
  const float* W_in  = (const float*)d_in[2];
  const float* b_in  = (const float*)d_in[3];
  const float* W_out = (const float*)d_in[4];
  const float* b_out = (const float*)d_in[5];
  const float* W_kv  = (const float*)d_in[6];
  const float* b_kv  = (const float*)d_in[7];
  float* out = (float*)d_out;

  char* ws = (char*)d_ws;
  size_t off = 0;
  auto carve = [&](size_t bytes) -> void* {
    void* p = ws + off;
    off = (off + bytes + 255) & ~(size_t)255;
    return p;
  };
  int*            idx    = (int*)           carve((size_t)T_ * Hh * 4);
  float*          gate   = (float*)         carve((size_t)T_ * Hh * 4);
  float*          bstats = (float*)         carve((size_t)49 * NB2 * 4);
  float*          stats2 = (float*)         carve(256);
  float*          lpart  = (float*)         carve((size_t)Bb * Hh * Nn * 4);
  float*          lgate  = (float*)         carve((size_t)T_ * KS * Ee * 4);
  unsigned short* xb     = (unsigned short*)carve((size_t)T_ * Cc * 2);
  unsigned short* BqkvT  = (unsigned short*)carve((size_t)(Ee * Dd + 128) * Cc * 2);
  unsigned short* BkvT   = BqkvT + (size_t)Ee * Dd * Cc;
  unsigned short* BrT    = (unsigned short*)carve((size_t)Cc * KR * 2);
  unsigned short* kbuf   = (unsigned short*)carve((size_t)T_ * Dd * 2);
  unsigned short* vtbuf  = (unsigned short*)carve((size_t)T_ * Dd * 2);
  unsigned short* qallb  = (unsigned short*)carve((size_t)T_ * Ee * Dd * 2);
  float*          opart  = (float*)         carve((size_t)Bb * Hh * Nn * Dd * 4);
  unsigned short* xeg    = (unsigned short*)carve((size_t)T_ * KR * 2);

  // merged weight conversions (one dispatch)
  convert_all_kernel<<<888, 256, 0, stream>>>(
      W_in, W_out, b_out, W_kv, BqkvT, BrT, BkvT);

  // gating (+ fused x -> bf16)
  gate1_kernel<<<dim3(T_ / 256, KS), 256, 0, stream>>>(x, wg, lgate, xb);
  gate2_kernel<<<NB2, 256, 0, stream>>>(lgate, idx, gate, bstats);

  // fused qall + kv GEMM: 64x64 tiles, 1D grid 1664, T1 XCD swizzle (NT=26)
  gemm_bt_kernel<1, 64, 26><<<(T_ / 64) * 26, 256, 0, stream>>>(
      xb, BqkvT, b_in, b_kv, qallb, kbuf, vtbuf, Cc, 1536);

  // attention: grid (32, 24) = 768 blocks (3/CU at 48 KB LDS), pipelined
  attn_kernel<<<dim3(Nn / 64, Bb * Hh), 256, 0, stream>>>(
      qallb, idx, kbuf, vtbuf, opart, lpart);

  // scatter (+ gate/l fold)
  scatter_kernel<<<T_, 256, 0, stream>>>(opart, lpart, idx, gate, xeg);

  // out = xeg @ BrT^T -> f32: 64x64 tiles, 1D grid 768, T1 XCD swizzle (NT=12)
  gemm_bt_kernel<0, 64, 12><<<(T_ / 64) * (Cc / 64), 256, 0, stream>>>(
      xeg, BrT, nullptr, nullptr, out, nullptr, nullptr, KR, Cc);

  // aux loss
  aux1_kernel<<<49, 256, 0, stream>>>(bstats, stats2);
  aux2_kernel<<<1, 64, 0, stream>>>(stats2, out, out_size);
}

// Round 9
// 191.067 us; speedup vs baseline: 1.1292x; 1.1058x over previous
//
#include <hip/hip_runtime.h>
#include <hip/hip_bf16.h>

// Problem constants
#define T_  4096
#define Bb  2
#define Nn  2048
#define Cc  768
#define Ee  24
#define Dd  64
#define Hh  12
#define KR  1600   // reduce GEMM K: 1536 (W_out) + 24 (b_out) + 40 pad (mult of 64)
#define KS  16     // gate k-split
#define KC  48     // 768 / KS
#define NB2 1024   // gate2 block count (T_/4)
#define SCL 0.18033688f   // 0.125 * log2(e) — folded into q at GEMM epilogue

typedef __attribute__((ext_vector_type(8))) short bf16x8;
typedef __attribute__((ext_vector_type(4))) short bf16x4;
typedef __attribute__((ext_vector_type(4))) float f32x4;

__device__ __forceinline__ unsigned short f2bf(float f) {
  union { float f; unsigned int i; } u; u.f = f;
  unsigned int r = u.i + 0x7FFFu + ((u.i >> 16) & 1u);
  return (unsigned short)(r >> 16);
}

__device__ __forceinline__ void gload16(const void* g, void* l) {
  __builtin_amdgcn_global_load_lds(
      (const __attribute__((address_space(1))) void*)g,
      (__attribute__((address_space(3))) void*)l, 16, 0, 0);
}

// ---------------------------------------------------------------------------
// Merged weight conversion (one dispatch): flat grid
//   blocks [0,288)    : W_in -> BqT   (e = i/12, c0 = (i%12)*64)
//   blocks [288,888)  : [W_out;b_out;pad] -> BrT (50 k-tiles x 12 n-tiles)
//   blocks [888,900)  : W_kv -> BkvT
// ---------------------------------------------------------------------------
__global__ __launch_bounds__(256) void convert_all_kernel(
    const float* __restrict__ W_in, const float* __restrict__ W_out,
    const float* __restrict__ b_out, const float* __restrict__ W_kv,
    unsigned short* __restrict__ BqT, unsigned short* __restrict__ BrT,
    unsigned short* __restrict__ BkvT)
{
  __shared__ float ls[64 * 129];
  const int bid = blockIdx.x, tid = threadIdx.x;
  if (bid < 288) {
    const int e = bid / 12, c0 = (bid % 12) * 64;
    #pragma unroll
    for (int i = 0; i < 16; ++i) {
      int L = tid + i * 256, c = L >> 6, d = L & 63;
      ls[c * 65 + d] = W_in[(size_t)e * Cc * Dd + (size_t)(c0 + c) * Dd + d];
    }
    __syncthreads();
    #pragma unroll
    for (int i = 0; i < 16; ++i) {
      int L = tid + i * 256, d = L >> 6, c = L & 63;
      BqT[(size_t)(e * Dd + d) * Cc + c0 + c] = f2bf(ls[c * 65 + d]);
    }
  } else if (bid < 888) {
    const int i2 = bid - 288;
    const int k0 = (i2 / 12) * 32, n0 = (i2 % 12) * 64;
    #pragma unroll
    for (int i = 0; i < 8; ++i) {
      int L = tid + i * 256, k = L >> 6, n = L & 63;
      int kk = k0 + k;
      float v = (kk < 1536) ? W_out[(size_t)kk * Cc + n0 + n]
              : (kk < 1560) ? b_out[(size_t)(kk - 1536) * Cc + n0 + n] : 0.f;
      ls[k * 65 + n] = v;
    }
    __syncthreads();
    #pragma unroll
    for (int i = 0; i < 8; ++i) {
      int L = tid + i * 256, n = L >> 5, k = L & 31;
      BrT[(size_t)(n0 + n) * KR + k0 + k] = f2bf(ls[k * 65 + n]);
    }
  } else {
    const int c0 = (bid - 888) * 64;
    #pragma unroll
    for (int i = 0; i < 32; ++i) {
      int L = tid + i * 256, c = L >> 7, j = L & 127;
      ls[c * 129 + j] = W_kv[(size_t)(c0 + c) * 128 + j];
    }
    __syncthreads();
    #pragma unroll
    for (int i = 0; i < 32; ++i) {
      int L = tid + i * 256, j = L >> 6, c = L & 63;
      BkvT[(size_t)j * Cc + c0 + c] = f2bf(ls[c * 129 + j]);
    }
  }
}

// ---------------------------------------------------------------------------
// bf16 MFMA GEMM: C = A[M][K] @ BT[N][K]^T (+bias).  Tile 64x64, BK=64.
// vs R5 (BK=32): (1) K-steps HALVED (qkv 24->12, reduce 49->25) -> half the
// barrier-drain events; (2) LDS tiles are 128-B rows staged with the attn
// kernel's pre-swizzled-source global_load_lds pattern and read with the
// (quad^xl) XOR offsets — the exact pattern that measures ZERO
// SQ_LDS_BANK_CONFLICT in attn (the old 64-B-row unswizzled reads showed
// 2.55M conflicts in R7's fused variant).  T1 XCD swizzle REVERTED (R8: −8us;
// round-robin XCD assignment already gives each XCD 8 m-panels x all n).
// MODE 0: f32 out (reduce GEMM).  MODE 1: fused qall+kv epilogue (unchanged).
// ---------------------------------------------------------------------------
template<int MODE>
__global__ __launch_bounds__(256) void gemm_bt_kernel(
    const unsigned short* __restrict__ A, const unsigned short* __restrict__ BT,
    const float* __restrict__ bias, const float* __restrict__ bias2,
    void* __restrict__ Cout, void* __restrict__ Cout2, void* __restrict__ Cout3,
    int K, int ldc)
{
  constexpr int BM = 64, BN = 64, MI = 2, NI = 2;
  __shared__ __align__(16) unsigned short As[2][BM * 64];
  __shared__ __align__(16) unsigned short Bs[2][BN * 64];
  const int tid = threadIdx.x, w = tid >> 6, lane = tid & 63;
  const int quad = lane >> 4, nl = lane & 15;
  const int m0 = blockIdx.x * BM, n0 = blockIdx.y * BN;
  const int mw = (w & 1) * 32, nw = (w >> 1) * 32;

  f32x4 acc[MI][NI];
  #pragma unroll
  for (int i = 0; i < MI; ++i)
    #pragma unroll
    for (int j = 0; j < NI; ++j) acc[i][j] = (f32x4){0.f, 0.f, 0.f, 0.f};

  // attn-style swizzled staging/read offsets (verified 0 bank conflicts)
  const int sr  = lane >> 3;                 // row within 8-row stage chunk
  const int cbd = (lane & 7) ^ sr;           // pre-swizzled source chunk
  const int xl  = nl & 15 & 7;               // nl & 7
  const int ca0 = (quad ^ xl) * 8;           // K-half 0 chunk offset (shorts)
  const int ca1 = ((quad + 4) ^ xl) * 8;     // K-half 1

  const unsigned short* abase = A + (size_t)(m0 + w * 16 + sr) * K + cbd * 8;
  const unsigned short* bbase = BT + (size_t)(n0 + w * 16 + sr) * K + cbd * 8;

  auto STAGE = [&](int bi, int k0) {
    #pragma unroll
    for (int i = 0; i < 2; ++i) {
      gload16(abase + (size_t)(i * 8) * K + k0, &As[bi][(w * 16 + i * 8) * 64]);
      gload16(bbase + (size_t)(i * 8) * K + k0, &Bs[bi][(w * 16 + i * 8) * 64]);
    }
  };

  const int nt = K / 64;
  STAGE(0, 0);
  __syncthreads();
  for (int t = 0; t < nt; ++t) {
    const int cur = t & 1;
    if (t + 1 < nt) STAGE(cur ^ 1, (t + 1) * 64);   // issue next BEFORE compute

    bf16x8 af0[MI], af1[MI], bf0[NI], bf1[NI];
    #pragma unroll
    for (int mi = 0; mi < MI; ++mi) {
      const unsigned short* ar = &As[cur][(mw + mi * 16 + nl) * 64];
      af0[mi] = *(const bf16x8*)(ar + ca0);
      af1[mi] = *(const bf16x8*)(ar + ca1);
    }
    #pragma unroll
    for (int ni = 0; ni < NI; ++ni) {
      const unsigned short* br = &Bs[cur][(nw + ni * 16 + nl) * 64];
      bf0[ni] = *(const bf16x8*)(br + ca0);
      bf1[ni] = *(const bf16x8*)(br + ca1);
    }
    #pragma unroll
    for (int mi = 0; mi < MI; ++mi)
      #pragma unroll
      for (int ni = 0; ni < NI; ++ni) {
        acc[mi][ni] = __builtin_amdgcn_mfma_f32_16x16x32_bf16(
            af0[mi], bf0[ni], acc[mi][ni], 0, 0, 0);
        acc[mi][ni] = __builtin_amdgcn_mfma_f32_16x16x32_bf16(
            af1[mi], bf1[ni], acc[mi][ni], 0, 0, 0);
      }

    __syncthreads();   // drain overlaps: loads had the compute phase to land
  }

  #pragma unroll
  for (int mi = 0; mi < MI; ++mi) {
    int rowb = m0 + mw + mi * 16 + quad * 4;
    int bb = rowb >> 11, nn = rowb & (Nn - 1);
    #pragma unroll
    for (int ni = 0; ni < NI; ++ni) {
      int col = n0 + nw + ni * 16 + nl;
      if (MODE == 0) {
        #pragma unroll
        for (int reg = 0; reg < 4; ++reg)
          ((float*)Cout)[(size_t)(rowb + reg) * ldc + col] = acc[mi][ni][reg];
      } else {
        if (col < 1536) {
          float bv = bias[col];
          #pragma unroll
          for (int reg = 0; reg < 4; ++reg)
            ((unsigned short*)Cout)[(size_t)(rowb + reg) * 1536 + col] =
                f2bf((acc[mi][ni][reg] + bv) * SCL);
        } else {
          int c2 = col - 1536;
          float bv = bias2[c2];
          if (c2 < Dd) {
            #pragma unroll
            for (int reg = 0; reg < 4; ++reg)
              ((unsigned short*)Cout2)[((size_t)bb * Nn + nn + reg) * Dd + c2] =
                  f2bf(acc[mi][ni][reg] + bv);
          } else {
            int p6 = nn & 63;
            int np = (nn & ~63) | (p6 & 0x23)
                   | (((p6 >> 4) & 1) << 2) | (((p6 >> 2) & 3) << 3);
            ushort4 v;
            v.x = f2bf(acc[mi][ni][0] + bv);
            v.y = f2bf(acc[mi][ni][1] + bv);
            v.z = f2bf(acc[mi][ni][2] + bv);
            v.w = f2bf(acc[mi][ni][3] + bv);
            *(ushort4*)((unsigned short*)Cout3 +
                        ((size_t)bb * Dd + (c2 - Dd)) * Nn + np) = v;
          }
        }
      }
    }
  }
}

// ---------------------------------------------------------------------------
// gate1: partial logits + fused x->bf16 conversion
// ---------------------------------------------------------------------------
#define XPAD 52
__global__ __launch_bounds__(256) void gate1_kernel(
    const float* __restrict__ x, const float* __restrict__ wg,
    float* __restrict__ partial, unsigned short* __restrict__ xb)
{
  __shared__ __align__(16) float xs[256 * XPAD];
  __shared__ __align__(16) float wsT[Ee * KC];
  const int tid = threadIdx.x;
  const int t0 = blockIdx.x * 256;
  const int s = blockIdx.y, k0 = s * KC;

  #pragma unroll
  for (int i = 0; i < 12; ++i) {
    int f = tid + i * 256;
    int token = f / 12, j = f % 12;
    size_t gofs = (size_t)(t0 + token) * Cc + k0 + j * 4;
    float4 v = *(const float4*)&x[gofs];
    *(float4*)&xs[token * XPAD + j * 4] = v;
    ushort4 o;
    o.x = f2bf(v.x); o.y = f2bf(v.y); o.z = f2bf(v.z); o.w = f2bf(v.w);
    *(ushort4*)&xb[gofs] = o;
  }
  for (int i = tid; i < Ee * KC; i += 256)
    wsT[(i % Ee) * KC + i / Ee] = wg[k0 * Ee + i];
  __syncthreads();

  float xr[KC];
  #pragma unroll
  for (int kg = 0; kg < KC / 4; ++kg)
    *(float4*)&xr[kg * 4] = *(const float4*)&xs[tid * XPAD + kg * 4];

  float acc[Ee];
  #pragma unroll
  for (int e = 0; e < Ee; ++e) acc[e] = 0.f;
  #pragma unroll
  for (int e = 0; e < Ee; ++e) {
    #pragma unroll
    for (int kg = 0; kg < KC / 4; ++kg) {
      float4 wv = *(const float4*)&wsT[e * KC + kg * 4];
      acc[e] += xr[kg * 4 + 0] * wv.x + xr[kg * 4 + 1] * wv.y
              + xr[kg * 4 + 2] * wv.z + xr[kg * 4 + 3] * wv.w;
    }
  }

  float* dst = partial + ((size_t)(t0 + tid) * KS + s) * Ee;
  #pragma unroll
  for (int eg = 0; eg < Ee / 4; ++eg)
    *(float4*)&dst[eg * 4] = *(float4*)&acc[eg * 4];
}

// ---------------------------------------------------------------------------
// gate2: logits -> softmax -> top-12 -> gates; block stats -> bstats
// ---------------------------------------------------------------------------
__global__ __launch_bounds__(256) void gate2_kernel(
    const float* __restrict__ partial,
    int* __restrict__ idx, float* __restrict__ gate, float* __restrict__ bstats)
{
  __shared__ float xls[4][KS * Ee];
  __shared__ float sacc[49];
  const int tid = threadIdx.x;
  const int w = tid >> 6, lane = tid & 63;
  const int t = blockIdx.x * 4 + w;

  if (tid < 49) sacc[tid] = 0.f;

  const float* p = partial + (size_t)t * (KS * Ee);
  #pragma unroll
  for (int i = 0; i < 6; ++i) xls[w][lane + i * 64] = p[lane + i * 64];

  float logit = -1e30f;
  if (lane < Ee) {
    float acc = 0.f;
    #pragma unroll
    for (int s = 0; s < KS; ++s) acc += xls[w][s * Ee + lane];
    logit = acc;
  }
  float m = logit;
  for (int o = 32; o; o >>= 1) m = fmaxf(m, __shfl_xor(m, o));
  float pr = (lane < Ee) ? expf(logit - m) : 0.f;
  float s = pr;
  for (int o = 32; o; o >>= 1) s += __shfl_xor(s, o);
  float prob = pr / s;
  float lse = m + logf(s);

  bool sel = false;
  float my_p = 0.f; int my_e = -1;
  for (int h = 0; h < Hh; ++h) {
    float v = (lane < Ee && !sel) ? prob : -1.f;
    int ix = lane;
    for (int o = 32; o; o >>= 1) {
      float ov = __shfl_xor(v, o); int oi = __shfl_xor(ix, o);
      if (ov > v || (ov == v && oi < ix)) { v = ov; ix = oi; }
    }
    if (lane == ix) sel = true;
    if (lane == h) { my_p = v; my_e = ix; }
  }
  float gsum = (lane < Hh) ? my_p : 0.f;
  for (int o = 32; o; o >>= 1) gsum += __shfl_xor(gsum, o);
  if (lane < Hh) {
    idx[t * Hh + lane] = my_e;
    gate[t * Hh + lane] = my_p / (gsum + 1e-6f);
  }

  __syncthreads();
  if (lane < Ee) atomicAdd(&sacc[lane], prob);
  if (lane < Hh) atomicAdd(&sacc[24 + my_e], 1.0f);
  if (lane == 0) atomicAdd(&sacc[48], lse * lse);
  __syncthreads();
  if (tid < 49) bstats[(size_t)tid * NB2 + blockIdx.x] = sacc[tid];
}

// ---------------------------------------------------------------------------
// Flash attention (UNCHANGED from the 203us-best R5 config): transposed,
// 16 q/wave, in-register P, PV at K=32, 3-deep rotating LDS buffers (48 KB),
// 2-tile prefetch via global_load_lds, counted s_waitcnt vmcnt(8).
// Grid (N/64, B*H) = 768 blocks = 3 blocks/CU at 48 KB LDS.
// Six structural variants measured 40-47us — converged; do not touch.
// ---------------------------------------------------------------------------
__global__ __launch_bounds__(256, 3) void attn_kernel(
    const unsigned short* __restrict__ qallb, const int* __restrict__ idx,
    const unsigned short* __restrict__ kbuf, const unsigned short* __restrict__ vtbuf,
    float* __restrict__ opart, float* __restrict__ lpart)
{
  __shared__ __align__(16) unsigned short ksl[3][64 * 64];  // K tiles [key][d], swizzled
  __shared__ __align__(16) unsigned short vtl[3][64 * 64];  // V^T tiles [d][key-perm]

  const int tid = threadIdx.x;
  const int w = tid >> 6, lane = tid & 63;
  const int quad = lane >> 4, nl = lane & 15;
  const int bh = blockIdx.y;
  const int b = bh / Hh, h = bh - b * Hh;
  const int qw = blockIdx.x * 64 + w * 16;      // wave's 16 queries

  // Q B-frags (gathered via expert idx; pre-scaled by SCL at GEMM epilogue)
  const int tq = b * Nn + qw + nl;
  const int eq = idx[tq * Hh + h];
  const unsigned short* qrow = qallb + (size_t)tq * (Ee * Dd) + eq * Dd + quad * 8;
  const bf16x8 qB0 = *(const bf16x8*)(qrow);
  const bf16x8 qB1 = *(const bf16x8*)(qrow + 32);

  f32x4 acc[4];
  #pragma unroll
  for (int dg = 0; dg < 4; ++dg) acc[dg] = (f32x4){0.f, 0.f, 0.f, 0.f};
  float l = 0.f;

  const int sr  = lane >> 3;
  const int cbd = (lane & 7) ^ sr;              // XOR-swizzled source chunk
  const int xl  = nl & 7;
  const int ca0 = (quad ^ xl) * 8;              // b128 chunk offsets (K and V)
  const int ca1 = ((quad + 4) ^ xl) * 8;

  // wave-level staging bases (each wave stages rows w*16..w*16+15 of a tile)
  const unsigned short* kgbase =
      kbuf + ((size_t)b * Nn + w * 16 + sr) * Dd + cbd * 8;
  const unsigned short* vgbase =
      vtbuf + ((size_t)b * Dd + w * 16 + sr) * Nn + cbd * 8;

  auto STAGE = [&](int bi, int t) {
    const int j0 = t * 64;
    #pragma unroll
    for (int i = 0; i < 2; ++i) {
      gload16(kgbase + (size_t)(j0 + i * 8) * Dd, &ksl[bi][(w * 16 + i * 8) * 64]);
      gload16(vgbase + (size_t)(i * 8) * Nn + j0, &vtl[bi][(w * 16 + i * 8) * 64]);
    }
  };

  auto COMPUTE = [&](const unsigned short* ks_, const unsigned short* vt_) {
    __builtin_amdgcn_s_setprio(1);
    // --- S^T = K·Q^T ---
    bf16x4 pf[4];
    #pragma unroll
    for (int kg = 0; kg < 4; ++kg) {
      const unsigned short* kr = ks_ + (kg * 16 + nl) * 64;
      bf16x8 a0 = *(const bf16x8*)(kr + ca0);
      bf16x8 a1 = *(const bf16x8*)(kr + ca1);
      f32x4 c = {0.f, 0.f, 0.f, 0.f};
      c = __builtin_amdgcn_mfma_f32_16x16x32_bf16(a0, qB0, c, 0, 0, 0);
      c = __builtin_amdgcn_mfma_f32_16x16x32_bf16(a1, qB1, c, 0, 0, 0);
      float p0 = __builtin_amdgcn_exp2f(c[0]);
      float p1 = __builtin_amdgcn_exp2f(c[1]);
      float p2 = __builtin_amdgcn_exp2f(c[2]);
      float p3 = __builtin_amdgcn_exp2f(c[3]);
      l += (p0 + p1) + (p2 + p3);
      union { __hip_bfloat162 h2[2]; bf16x4 v; } pk;
      pk.h2[0] = __float22bfloat162_rn(float2{p0, p1});
      pk.h2[1] = __float22bfloat162_rn(float2{p2, p3});
      pf[kg] = pk.v;
    }
    bf16x8 pb0 = __builtin_shufflevector(pf[0], pf[1], 0, 1, 2, 3, 4, 5, 6, 7);
    bf16x8 pb1 = __builtin_shufflevector(pf[2], pf[3], 0, 1, 2, 3, 4, 5, 6, 7);
    // --- O^T += V^T·P^T at K=32 ---
    #pragma unroll
    for (int dg = 0; dg < 4; ++dg) {
      const unsigned short* vrow = vt_ + (dg * 16 + nl) * 64;
      bf16x8 v0 = *(const bf16x8*)(vrow + ca0);
      bf16x8 v1 = *(const bf16x8*)(vrow + ca1);
      acc[dg] = __builtin_amdgcn_mfma_f32_16x16x32_bf16(v0, pb0, acc[dg], 0, 0, 0);
      acc[dg] = __builtin_amdgcn_mfma_f32_16x16x32_bf16(v1, pb1, acc[dg], 0, 0, 0);
    }
    __builtin_amdgcn_s_setprio(0);
  };

  // ---- software pipeline: 32 tiles, 2-deep prefetch, 3 rotating buffers ----
  STAGE(0, 0);
  STAGE(1, 1);
  #pragma unroll 1
  for (int t = 0; t < 30; t += 3) {
    STAGE(2, t + 2);
    asm volatile("s_waitcnt vmcnt(8)" ::: "memory");
    __builtin_amdgcn_s_barrier();
    __builtin_amdgcn_sched_barrier(0);
    COMPUTE(ksl[0], vtl[0]);
    __builtin_amdgcn_sched_barrier(0);
    asm volatile("" ::: "memory");
    __builtin_amdgcn_s_barrier();

    STAGE(0, t + 3);
    asm volatile("s_waitcnt vmcnt(8)" ::: "memory");
    __builtin_amdgcn_s_barrier();
    __builtin_amdgcn_sched_barrier(0);
    COMPUTE(ksl[1], vtl[1]);
    __builtin_amdgcn_sched_barrier(0);
    asm volatile("" ::: "memory");
    __builtin_amdgcn_s_barrier();

    STAGE(1, t + 4);
    asm volatile("s_waitcnt vmcnt(8)" ::: "memory");
    __builtin_amdgcn_s_barrier();
    __builtin_amdgcn_sched_barrier(0);
    COMPUTE(ksl[2], vtl[2]);
    __builtin_amdgcn_sched_barrier(0);
    asm volatile("" ::: "memory");
    __builtin_amdgcn_s_barrier();
  }
  asm volatile("s_waitcnt vmcnt(4)" ::: "memory");
  __builtin_amdgcn_s_barrier();
  __builtin_amdgcn_sched_barrier(0);
  COMPUTE(ksl[0], vtl[0]);
  __builtin_amdgcn_sched_barrier(0);
  asm volatile("s_waitcnt vmcnt(0)" ::: "memory");
  __builtin_amdgcn_s_barrier();
  __builtin_amdgcn_sched_barrier(0);
  COMPUTE(ksl[1], vtl[1]);

  float lg = l;
  lg += __shfl_xor(lg, 16);
  lg += __shfl_xor(lg, 32);
  if (lane < 16)
    lpart[(size_t)bh * Nn + qw + nl] = lg;
  float* orow = opart + ((size_t)bh * Nn + qw + nl) * Dd + quad * 4;
  #pragma unroll
  for (int dg = 0; dg < 4; ++dg) {
    float4 o;
    o.x = acc[dg][0]; o.y = acc[dg][1];
    o.z = acc[dg][2]; o.w = acc[dg][3];
    *(float4*)(orow + dg * 16) = o;
  }
}

// ---------------------------------------------------------------------------
// Scatter + combine: xeg row from opart/l with gate folded in.
// Writes all KR=1600 cols (zeros beyond 1560) so the GEMM pad reads 0.
// ---------------------------------------------------------------------------
__global__ __launch_bounds__(256) void scatter_kernel(
    const float* __restrict__ opart, const float* __restrict__ lpart,
    const int* __restrict__ idx, const float* __restrict__ gate,
    unsigned short* __restrict__ xeg)
{
  __shared__ int   sel[Ee];
  __shared__ float glh[Hh];   // gate / l
  __shared__ float gg[Hh];    // raw gate (for the dense-gate K-rows)
  const int t = blockIdx.x, b = t >> 11, nn = t & (Nn - 1);
  const int tid = threadIdx.x;
  if (tid < Ee) sel[tid] = -1;
  __syncthreads();
  if (tid < Hh) {
    int e = idx[t * Hh + tid];
    sel[e] = tid;
    float g = gate[t * Hh + tid];
    gg[tid] = g;
    size_t row = (size_t)(b * Hh + tid) * Nn + nn;
    glh[tid] = g / lpart[row];
  }
  __syncthreads();
  for (int c = tid; c < KR; c += 256) {
    float v = 0.f;
    if (c < 1536) {
      int e = c >> 6, h = sel[e];
      if (h >= 0) {
        size_t oofs = ((size_t)(b * Hh + h) * Nn + nn) * Dd + (c & 63);
        v = glh[h] * opart[oofs];
      }
    } else if (c < 1560) {
      int h = sel[c - 1536];
      if (h >= 0) v = gg[h];
    }
    xeg[(size_t)t * KR + c] = f2bf(v);
  }
}

// ---------------------------------------------------------------------------
// aux1: parallel bstats row-sum -> stats2[49];  aux2: finalize
// ---------------------------------------------------------------------------
__global__ __launch_bounds__(256) void aux1_kernel(
    const float* __restrict__ bstats, float* __restrict__ stats2)
{
  __shared__ float r[4];
  const int j = blockIdx.x, tid = threadIdx.x;
  float4 v = *(const float4*)&bstats[(size_t)j * NB2 + tid * 4];
  float s = (v.x + v.y) + (v.z + v.w);
  for (int o = 32; o; o >>= 1) s += __shfl_xor(s, o);
  if ((tid & 63) == 0) r[tid >> 6] = s;
  __syncthreads();
  if (tid == 0) stats2[j] = (r[0] + r[1]) + (r[2] + r[3]);
}

__global__ void aux2_kernel(const float* __restrict__ stats2,
                            float* __restrict__ out, int out_size)
{
  const int lane = threadIdx.x;
  float a = (lane < Ee) ? stats2[lane] : 0.f;
  float b = (lane < Ee) ? stats2[24 + lane] : 0.f;
  float pt = a, ft = b, sw = a * b;
  for (int o = 32; o; o >>= 1) {
    pt += __shfl_xor(pt, o); ft += __shfl_xor(ft, o); sw += __shfl_xor(sw, o);
  }
  if (lane == 0) {
    float sswitch = (float)Ee * sw / (pt * ft);
    float z = stats2[48] * (1.0f / (float)T_);
    out[out_size - 1] = 0.1f * sswitch + 0.001f * z;
  }
}

// ---------------------------------------------------------------------------
extern "C" void kernel_launch(void* const* d_in, const int* in_sizes, int n_in,
                              void* d_out, int out_size, void* d_ws, size_t ws_size,
                              hipStream_t stream)
{
  const float* x     = (const float*)d_in[0];
  const float* wg    = (const float*)d_in[1];
  const float* W_in  = (const float*)d_in[2];
  const float* b_in  = (const float*)d_in[3];
  const float* W_out = (const float*)d_in[4];
  const float* b_out = (const float*)d_in[5];
  const float* W_kv  = (const float*)d_in[6];
  const float* b_kv  = (const float*)d_in[7];
  float* out = (float*)d_out;

  char* ws = (char*)d_ws;
  size_t off = 0;
  auto carve = [&](size_t bytes) -> void* {
    void* p = ws + off;
    off = (off + bytes + 255) & ~(size_t)255;
    return p;
  };
  int*            idx    = (int*)           carve((size_t)T_ * Hh * 4);
  float*          gate   = (float*)         carve((size_t)T_ * Hh * 4);
  float*          bstats = (float*)         carve((size_t)49 * NB2 * 4);
  float*          stats2 = (float*)         carve(256);
  float*          lpart  = (float*)         carve((size_t)Bb * Hh * Nn * 4);
  float*          lgate  = (float*)         carve((size_t)T_ * KS * Ee * 4);
  unsigned short* xb     = (unsigned short*)carve((size_t)T_ * Cc * 2);
  unsigned short* BqkvT  = (unsigned short*)carve((size_t)(Ee * Dd + 128) * Cc * 2);
  unsigned short* BkvT   = BqkvT + (size_t)Ee * Dd * Cc;
  unsigned short* BrT    = (unsigned short*)carve((size_t)Cc * KR * 2);
  unsigned short* kbuf   = (unsigned short*)carve((size_t)T_ * Dd * 2);
  unsigned short* vtbuf  = (unsigned short*)carve((size_t)T_ * Dd * 2);
  unsigned short* qallb  = (unsigned short*)carve((size_t)T_ * Ee * Dd * 2);
  float*          opart  = (float*)         carve((size_t)Bb * Hh * Nn * Dd * 4);
  unsigned short* xeg    = (unsigned short*)carve((size_t)T_ * KR * 2);

  // merged weight conversions (one dispatch)
  convert_all_kernel<<<900, 256, 0, stream>>>(
      W_in, W_out, b_out, W_kv, BqkvT, BrT, BkvT);

  // gating (+ fused x -> bf16)
  gate1_kernel<<<dim3(T_ / 256, KS), 256, 0, stream>>>(x, wg, lgate, xb);
  gate2_kernel<<<NB2, 256, 0, stream>>>(lgate, idx, gate, bstats);

  // fused qall + kv GEMM: 64x64 tiles, BK=64, grid (64, 26)
  gemm_bt_kernel<1><<<dim3(T_ / 64, 26), 256, 0, stream>>>(
      xb, BqkvT, b_in, b_kv, qallb, kbuf, vtbuf, Cc, 1536);

  // attention: grid (32, 24) = 768 blocks (3/CU at 48 KB LDS), pipelined
  attn_kernel<<<dim3(Nn / 64, Bb * Hh), 256, 0, stream>>>(
      qallb, idx, kbuf, vtbuf, opart, lpart);

  // scatter (+ gate/l fold)
  scatter_kernel<<<T_, 256, 0, stream>>>(opart, lpart, idx, gate, xeg);

  // out = xeg @ BrT^T -> f32: 64x64 tiles, BK=64, grid (64, 12)
  gemm_bt_kernel<0><<<dim3(T_ / 64, Cc / 64), 256, 0, stream>>>(
      xeg, BrT, nullptr, nullptr, out, nullptr, nullptr, KR, Cc);

  // aux loss
  aux1_kernel<<<49, 256, 0, stream>>>(bstats, stats2);
  aux2_kernel<<<1, 64, 0, stream>>>(stats2, out, out_size);
}

// Round 10
// 183.800 us; speedup vs baseline: 1.1738x; 1.0395x over previous
//
#include <hip/hip_runtime.h>
#include <hip/hip_bf16.h>

// Problem constants
#define T_  4096
#define Bb  2
#define Nn  2048
#define Cc  768
#define Ee  24
#define Dd  64
#define Hh  12
#define KR  1600   // reduce GEMM K: 1536 (W_out) + 24 (b_out) + 40 pad (mult of 64)
#define KS  16     // gate k-split
#define KC  48     // 768 / KS
#define NB2 1024   // gate2 block count (T_/4)
#define SCL 0.18033688f   // 0.125 * log2(e) — folded into q at GEMM epilogue

typedef __attribute__((ext_vector_type(8))) short bf16x8;
typedef __attribute__((ext_vector_type(4))) short bf16x4;
typedef __attribute__((ext_vector_type(4))) float f32x4;
typedef __attribute__((ext_vector_type(8))) unsigned short u16x8;

__device__ __forceinline__ unsigned short f2bf(float f) {
  union { float f; unsigned int i; } u; u.f = f;
  unsigned int r = u.i + 0x7FFFu + ((u.i >> 16) & 1u);
  return (unsigned short)(r >> 16);
}

__device__ __forceinline__ void gload16(const void* g, void* l) {
  __builtin_amdgcn_global_load_lds(
      (const __attribute__((address_space(1))) void*)g,
      (__attribute__((address_space(3))) void*)l, 16, 0, 0);
}

// ---------------------------------------------------------------------------
// Merged weight conversion (one dispatch): flat grid
//   blocks [0,288)    : W_in -> BqT   (e = i/12, c0 = (i%12)*64)
//   blocks [288,888)  : [W_out;b_out;pad] -> BrT (50 k-tiles x 12 n-tiles)
//   blocks [888,900)  : W_kv -> BkvT
// ---------------------------------------------------------------------------
__global__ __launch_bounds__(256) void convert_all_kernel(
    const float* __restrict__ W_in, const float* __restrict__ W_out,
    const float* __restrict__ b_out, const float* __restrict__ W_kv,
    unsigned short* __restrict__ BqT, unsigned short* __restrict__ BrT,
    unsigned short* __restrict__ BkvT)
{
  __shared__ float ls[64 * 129];
  const int bid = blockIdx.x, tid = threadIdx.x;
  if (bid < 288) {
    const int e = bid / 12, c0 = (bid % 12) * 64;
    #pragma unroll
    for (int i = 0; i < 16; ++i) {
      int L = tid + i * 256, c = L >> 6, d = L & 63;
      ls[c * 65 + d] = W_in[(size_t)e * Cc * Dd + (size_t)(c0 + c) * Dd + d];
    }
    __syncthreads();
    #pragma unroll
    for (int i = 0; i < 16; ++i) {
      int L = tid + i * 256, d = L >> 6, c = L & 63;
      BqT[(size_t)(e * Dd + d) * Cc + c0 + c] = f2bf(ls[c * 65 + d]);
    }
  } else if (bid < 888) {
    const int i2 = bid - 288;
    const int k0 = (i2 / 12) * 32, n0 = (i2 % 12) * 64;
    #pragma unroll
    for (int i = 0; i < 8; ++i) {
      int L = tid + i * 256, k = L >> 6, n = L & 63;
      int kk = k0 + k;
      float v = (kk < 1536) ? W_out[(size_t)kk * Cc + n0 + n]
              : (kk < 1560) ? b_out[(size_t)(kk - 1536) * Cc + n0 + n] : 0.f;
      ls[k * 65 + n] = v;
    }
    __syncthreads();
    #pragma unroll
    for (int i = 0; i < 8; ++i) {
      int L = tid + i * 256, n = L >> 5, k = L & 31;
      BrT[(size_t)(n0 + n) * KR + k0 + k] = f2bf(ls[k * 65 + n]);
    }
  } else {
    const int c0 = (bid - 888) * 64;
    #pragma unroll
    for (int i = 0; i < 32; ++i) {
      int L = tid + i * 256, c = L >> 7, j = L & 127;
      ls[c * 129 + j] = W_kv[(size_t)(c0 + c) * 128 + j];
    }
    __syncthreads();
    #pragma unroll
    for (int i = 0; i < 32; ++i) {
      int L = tid + i * 256, j = L >> 6, c = L & 63;
      BkvT[(size_t)j * Cc + c0 + c] = f2bf(ls[c * 129 + j]);
    }
  }
}

// ---------------------------------------------------------------------------
// bf16 MFMA GEMM: C = A[M][K] @ BT[N][K]^T (+bias).  Tile 64x64, BK=64.
// R9 structure (WIN, 191us): halved barrier count + attn-style XOR-swizzled
// LDS staging/reads (zero bank conflicts).  Unchanged this round.
// MODE 0: f32 out (reduce GEMM).  MODE 1: fused qall+kv epilogue.
// ---------------------------------------------------------------------------
template<int MODE>
__global__ __launch_bounds__(256) void gemm_bt_kernel(
    const unsigned short* __restrict__ A, const unsigned short* __restrict__ BT,
    const float* __restrict__ bias, const float* __restrict__ bias2,
    void* __restrict__ Cout, void* __restrict__ Cout2, void* __restrict__ Cout3,
    int K, int ldc)
{
  constexpr int BM = 64, BN = 64, MI = 2, NI = 2;
  __shared__ __align__(16) unsigned short As[2][BM * 64];
  __shared__ __align__(16) unsigned short Bs[2][BN * 64];
  const int tid = threadIdx.x, w = tid >> 6, lane = tid & 63;
  const int quad = lane >> 4, nl = lane & 15;
  const int m0 = blockIdx.x * BM, n0 = blockIdx.y * BN;
  const int mw = (w & 1) * 32, nw = (w >> 1) * 32;

  f32x4 acc[MI][NI];
  #pragma unroll
  for (int i = 0; i < MI; ++i)
    #pragma unroll
    for (int j = 0; j < NI; ++j) acc[i][j] = (f32x4){0.f, 0.f, 0.f, 0.f};

  // attn-style swizzled staging/read offsets (verified 0 bank conflicts)
  const int sr  = lane >> 3;                 // row within 8-row stage chunk
  const int cbd = (lane & 7) ^ sr;           // pre-swizzled source chunk
  const int xl  = nl & 7;
  const int ca0 = (quad ^ xl) * 8;           // K-half 0 chunk offset (shorts)
  const int ca1 = ((quad + 4) ^ xl) * 8;     // K-half 1

  const unsigned short* abase = A + (size_t)(m0 + w * 16 + sr) * K + cbd * 8;
  const unsigned short* bbase = BT + (size_t)(n0 + w * 16 + sr) * K + cbd * 8;

  auto STAGE = [&](int bi, int k0) {
    #pragma unroll
    for (int i = 0; i < 2; ++i) {
      gload16(abase + (size_t)(i * 8) * K + k0, &As[bi][(w * 16 + i * 8) * 64]);
      gload16(bbase + (size_t)(i * 8) * K + k0, &Bs[bi][(w * 16 + i * 8) * 64]);
    }
  };

  const int nt = K / 64;
  STAGE(0, 0);
  __syncthreads();
  for (int t = 0; t < nt; ++t) {
    const int cur = t & 1;
    if (t + 1 < nt) STAGE(cur ^ 1, (t + 1) * 64);   // issue next BEFORE compute

    bf16x8 af0[MI], af1[MI], bf0[NI], bf1[NI];
    #pragma unroll
    for (int mi = 0; mi < MI; ++mi) {
      const unsigned short* ar = &As[cur][(mw + mi * 16 + nl) * 64];
      af0[mi] = *(const bf16x8*)(ar + ca0);
      af1[mi] = *(const bf16x8*)(ar + ca1);
    }
    #pragma unroll
    for (int ni = 0; ni < NI; ++ni) {
      const unsigned short* br = &Bs[cur][(nw + ni * 16 + nl) * 64];
      bf0[ni] = *(const bf16x8*)(br + ca0);
      bf1[ni] = *(const bf16x8*)(br + ca1);
    }
    #pragma unroll
    for (int mi = 0; mi < MI; ++mi)
      #pragma unroll
      for (int ni = 0; ni < NI; ++ni) {
        acc[mi][ni] = __builtin_amdgcn_mfma_f32_16x16x32_bf16(
            af0[mi], bf0[ni], acc[mi][ni], 0, 0, 0);
        acc[mi][ni] = __builtin_amdgcn_mfma_f32_16x16x32_bf16(
            af1[mi], bf1[ni], acc[mi][ni], 0, 0, 0);
      }

    __syncthreads();   // drain overlaps: loads had the compute phase to land
  }

  #pragma unroll
  for (int mi = 0; mi < MI; ++mi) {
    int rowb = m0 + mw + mi * 16 + quad * 4;
    int bb = rowb >> 11, nn = rowb & (Nn - 1);
    #pragma unroll
    for (int ni = 0; ni < NI; ++ni) {
      int col = n0 + nw + ni * 16 + nl;
      if (MODE == 0) {
        #pragma unroll
        for (int reg = 0; reg < 4; ++reg)
          ((float*)Cout)[(size_t)(rowb + reg) * ldc + col] = acc[mi][ni][reg];
      } else {
        if (col < 1536) {
          float bv = bias[col];
          #pragma unroll
          for (int reg = 0; reg < 4; ++reg)
            ((unsigned short*)Cout)[(size_t)(rowb + reg) * 1536 + col] =
                f2bf((acc[mi][ni][reg] + bv) * SCL);
        } else {
          int c2 = col - 1536;
          float bv = bias2[c2];
          if (c2 < Dd) {
            #pragma unroll
            for (int reg = 0; reg < 4; ++reg)
              ((unsigned short*)Cout2)[((size_t)bb * Nn + nn + reg) * Dd + c2] =
                  f2bf(acc[mi][ni][reg] + bv);
          } else {
            int p6 = nn & 63;
            int np = (nn & ~63) | (p6 & 0x23)
                   | (((p6 >> 4) & 1) << 2) | (((p6 >> 2) & 3) << 3);
            ushort4 v;
            v.x = f2bf(acc[mi][ni][0] + bv);
            v.y = f2bf(acc[mi][ni][1] + bv);
            v.z = f2bf(acc[mi][ni][2] + bv);
            v.w = f2bf(acc[mi][ni][3] + bv);
            *(ushort4*)((unsigned short*)Cout3 +
                        ((size_t)bb * Dd + (c2 - Dd)) * Nn + np) = v;
          }
        }
      }
    }
  }
}

// ---------------------------------------------------------------------------
// gate1: partial logits + fused x->bf16 conversion
// ---------------------------------------------------------------------------
#define XPAD 52
__global__ __launch_bounds__(256) void gate1_kernel(
    const float* __restrict__ x, const float* __restrict__ wg,
    float* __restrict__ partial, unsigned short* __restrict__ xb)
{
  __shared__ __align__(16) float xs[256 * XPAD];
  __shared__ __align__(16) float wsT[Ee * KC];
  const int tid = threadIdx.x;
  const int t0 = blockIdx.x * 256;
  const int s = blockIdx.y, k0 = s * KC;

  #pragma unroll
  for (int i = 0; i < 12; ++i) {
    int f = tid + i * 256;
    int token = f / 12, j = f % 12;
    size_t gofs = (size_t)(t0 + token) * Cc + k0 + j * 4;
    float4 v = *(const float4*)&x[gofs];
    *(float4*)&xs[token * XPAD + j * 4] = v;
    ushort4 o;
    o.x = f2bf(v.x); o.y = f2bf(v.y); o.z = f2bf(v.z); o.w = f2bf(v.w);
    *(ushort4*)&xb[gofs] = o;
  }
  for (int i = tid; i < Ee * KC; i += 256)
    wsT[(i % Ee) * KC + i / Ee] = wg[k0 * Ee + i];
  __syncthreads();

  float xr[KC];
  #pragma unroll
  for (int kg = 0; kg < KC / 4; ++kg)
    *(float4*)&xr[kg * 4] = *(const float4*)&xs[tid * XPAD + kg * 4];

  float acc[Ee];
  #pragma unroll
  for (int e = 0; e < Ee; ++e) acc[e] = 0.f;
  #pragma unroll
  for (int e = 0; e < Ee; ++e) {
    #pragma unroll
    for (int kg = 0; kg < KC / 4; ++kg) {
      float4 wv = *(const float4*)&wsT[e * KC + kg * 4];
      acc[e] += xr[kg * 4 + 0] * wv.x + xr[kg * 4 + 1] * wv.y
              + xr[kg * 4 + 2] * wv.z + xr[kg * 4 + 3] * wv.w;
    }
  }

  float* dst = partial + ((size_t)(t0 + tid) * KS + s) * Ee;
  #pragma unroll
  for (int eg = 0; eg < Ee / 4; ++eg)
    *(float4*)&dst[eg * 4] = *(float4*)&acc[eg * 4];
}

// ---------------------------------------------------------------------------
// gate2: logits -> softmax -> top-12 -> gates; block stats -> bstats.
// NEW: also prepares each token's xeg row for the scatter-free pipeline:
//   - zero-fills cols [0,1536) (attn will overwrite the selected experts'
//     64-col blocks with gate*o/l)
//   - writes dense-gate cols 1536+e (gate value of the head that picked e),
//     zeros elsewhere incl. pad [1560,1600)
// ---------------------------------------------------------------------------
__global__ __launch_bounds__(256) void gate2_kernel(
    const float* __restrict__ partial,
    int* __restrict__ idx, float* __restrict__ gate, float* __restrict__ bstats,
    unsigned short* __restrict__ xeg)
{
  __shared__ float xls[4][KS * Ee];
  __shared__ float sacc[49];
  __shared__ unsigned short dens[4][64];
  const int tid = threadIdx.x;
  const int w = tid >> 6, lane = tid & 63;
  const int t = blockIdx.x * 4 + w;

  if (tid < 49) sacc[tid] = 0.f;
  dens[w][lane] = 0;

  const float* p = partial + (size_t)t * (KS * Ee);
  #pragma unroll
  for (int i = 0; i < 6; ++i) xls[w][lane + i * 64] = p[lane + i * 64];

  // zero-fill xeg cols [0,1536) for this token (3 x ushort8 per lane)
  {
    u16x8 z = (u16x8){0, 0, 0, 0, 0, 0, 0, 0};
    unsigned short* xrow = xeg + (size_t)t * KR;
    #pragma unroll
    for (int i = 0; i < 3; ++i)
      *(u16x8*)&xrow[(lane + i * 64) * 8] = z;
  }

  float logit = -1e30f;
  if (lane < Ee) {
    float acc = 0.f;
    #pragma unroll
    for (int s = 0; s < KS; ++s) acc += xls[w][s * Ee + lane];
    logit = acc;
  }
  float m = logit;
  for (int o = 32; o; o >>= 1) m = fmaxf(m, __shfl_xor(m, o));
  float pr = (lane < Ee) ? expf(logit - m) : 0.f;
  float s = pr;
  for (int o = 32; o; o >>= 1) s += __shfl_xor(s, o);
  float prob = pr / s;
  float lse = m + logf(s);

  bool sel = false;
  float my_p = 0.f; int my_e = -1;
  for (int h = 0; h < Hh; ++h) {
    float v = (lane < Ee && !sel) ? prob : -1.f;
    int ix = lane;
    for (int o = 32; o; o >>= 1) {
      float ov = __shfl_xor(v, o); int oi = __shfl_xor(ix, o);
      if (ov > v || (ov == v && oi < ix)) { v = ov; ix = oi; }
    }
    if (lane == ix) sel = true;
    if (lane == h) { my_p = v; my_e = ix; }
  }
  float gsum = (lane < Hh) ? my_p : 0.f;
  for (int o = 32; o; o >>= 1) gsum += __shfl_xor(gsum, o);
  float gval = my_p / (gsum + 1e-6f);
  if (lane < Hh) {
    idx[t * Hh + lane] = my_e;
    gate[t * Hh + lane] = gval;
  }

  __syncthreads();
  if (lane < Ee) atomicAdd(&sacc[lane], prob);
  if (lane < Hh) {
    atomicAdd(&sacc[24 + my_e], 1.0f);
    dens[w][my_e] = f2bf(gval);
  }
  if (lane == 0) atomicAdd(&sacc[48], lse * lse);
  __syncthreads();
  if (tid < 49) bstats[(size_t)tid * NB2 + blockIdx.x] = sacc[tid];

  // dense-gate + pad cols [1536,1600): one short per lane
  xeg[(size_t)t * KR + 1536 + lane] = dens[w][lane];
}

// ---------------------------------------------------------------------------
// Flash attention with FUSED combine epilogue (scatter kernel eliminated).
// Core loop UNCHANGED from the R5/R9 converged config: transposed, 16 q/wave,
// in-register P, PV at K=32, 3-deep rotating LDS buffers (48 KB), 2-tile
// prefetch via global_load_lds, counted s_waitcnt vmcnt(8).
// Epilogue: z=1 key-split means each block holds the COMPLETE softmax sum l
// at epilogue time, so it writes f2bf(gate * o / l) straight into the
// expert-gathered xeg layout — opart (25 MB f32 write + read), lpart, and
// the scatter dispatch are all deleted.
// ---------------------------------------------------------------------------
__global__ __launch_bounds__(256, 3) void attn_kernel(
    const unsigned short* __restrict__ qallb, const int* __restrict__ idx,
    const float* __restrict__ gate,
    const unsigned short* __restrict__ kbuf, const unsigned short* __restrict__ vtbuf,
    unsigned short* __restrict__ xeg)
{
  __shared__ __align__(16) unsigned short ksl[3][64 * 64];  // K tiles [key][d], swizzled
  __shared__ __align__(16) unsigned short vtl[3][64 * 64];  // V^T tiles [d][key-perm]

  const int tid = threadIdx.x;
  const int w = tid >> 6, lane = tid & 63;
  const int quad = lane >> 4, nl = lane & 15;
  const int bh = blockIdx.y;
  const int b = bh / Hh, h = bh - b * Hh;
  const int qw = blockIdx.x * 64 + w * 16;      // wave's 16 queries

  // Q B-frags (gathered via expert idx; pre-scaled by SCL at GEMM epilogue)
  const int tq = b * Nn + qw + nl;
  const int eq = idx[tq * Hh + h];
  const unsigned short* qrow = qallb + (size_t)tq * (Ee * Dd) + eq * Dd + quad * 8;
  const bf16x8 qB0 = *(const bf16x8*)(qrow);
  const bf16x8 qB1 = *(const bf16x8*)(qrow + 32);

  f32x4 acc[4];
  #pragma unroll
  for (int dg = 0; dg < 4; ++dg) acc[dg] = (f32x4){0.f, 0.f, 0.f, 0.f};
  float l = 0.f;

  const int sr  = lane >> 3;
  const int cbd = (lane & 7) ^ sr;              // XOR-swizzled source chunk
  const int xl  = nl & 7;
  const int ca0 = (quad ^ xl) * 8;              // b128 chunk offsets (K and V)
  const int ca1 = ((quad + 4) ^ xl) * 8;

  // wave-level staging bases (each wave stages rows w*16..w*16+15 of a tile)
  const unsigned short* kgbase =
      kbuf + ((size_t)b * Nn + w * 16 + sr) * Dd + cbd * 8;
  const unsigned short* vgbase =
      vtbuf + ((size_t)b * Dd + w * 16 + sr) * Nn + cbd * 8;

  auto STAGE = [&](int bi, int t) {
    const int j0 = t * 64;
    #pragma unroll
    for (int i = 0; i < 2; ++i) {
      gload16(kgbase + (size_t)(j0 + i * 8) * Dd, &ksl[bi][(w * 16 + i * 8) * 64]);
      gload16(vgbase + (size_t)(i * 8) * Nn + j0, &vtl[bi][(w * 16 + i * 8) * 64]);
    }
  };

  auto COMPUTE = [&](const unsigned short* ks_, const unsigned short* vt_) {
    __builtin_amdgcn_s_setprio(1);
    // --- S^T = K·Q^T ---
    bf16x4 pf[4];
    #pragma unroll
    for (int kg = 0; kg < 4; ++kg) {
      const unsigned short* kr = ks_ + (kg * 16 + nl) * 64;
      bf16x8 a0 = *(const bf16x8*)(kr + ca0);
      bf16x8 a1 = *(const bf16x8*)(kr + ca1);
      f32x4 c = {0.f, 0.f, 0.f, 0.f};
      c = __builtin_amdgcn_mfma_f32_16x16x32_bf16(a0, qB0, c, 0, 0, 0);
      c = __builtin_amdgcn_mfma_f32_16x16x32_bf16(a1, qB1, c, 0, 0, 0);
      float p0 = __builtin_amdgcn_exp2f(c[0]);
      float p1 = __builtin_amdgcn_exp2f(c[1]);
      float p2 = __builtin_amdgcn_exp2f(c[2]);
      float p3 = __builtin_amdgcn_exp2f(c[3]);
      l += (p0 + p1) + (p2 + p3);
      union { __hip_bfloat162 h2[2]; bf16x4 v; } pk;
      pk.h2[0] = __float22bfloat162_rn(float2{p0, p1});
      pk.h2[1] = __float22bfloat162_rn(float2{p2, p3});
      pf[kg] = pk.v;
    }
    bf16x8 pb0 = __builtin_shufflevector(pf[0], pf[1], 0, 1, 2, 3, 4, 5, 6, 7);
    bf16x8 pb1 = __builtin_shufflevector(pf[2], pf[3], 0, 1, 2, 3, 4, 5, 6, 7);
    // --- O^T += V^T·P^T at K=32 ---
    #pragma unroll
    for (int dg = 0; dg < 4; ++dg) {
      const unsigned short* vrow = vt_ + (dg * 16 + nl) * 64;
      bf16x8 v0 = *(const bf16x8*)(vrow + ca0);
      bf16x8 v1 = *(const bf16x8*)(vrow + ca1);
      acc[dg] = __builtin_amdgcn_mfma_f32_16x16x32_bf16(v0, pb0, acc[dg], 0, 0, 0);
      acc[dg] = __builtin_amdgcn_mfma_f32_16x16x32_bf16(v1, pb1, acc[dg], 0, 0, 0);
    }
    __builtin_amdgcn_s_setprio(0);
  };

  // ---- software pipeline: 32 tiles, 2-deep prefetch, 3 rotating buffers ----
  STAGE(0, 0);
  STAGE(1, 1);
  #pragma unroll 1
  for (int t = 0; t < 30; t += 3) {
    STAGE(2, t + 2);
    asm volatile("s_waitcnt vmcnt(8)" ::: "memory");
    __builtin_amdgcn_s_barrier();
    __builtin_amdgcn_sched_barrier(0);
    COMPUTE(ksl[0], vtl[0]);
    __builtin_amdgcn_sched_barrier(0);
    asm volatile("" ::: "memory");
    __builtin_amdgcn_s_barrier();

    STAGE(0, t + 3);
    asm volatile("s_waitcnt vmcnt(8)" ::: "memory");
    __builtin_amdgcn_s_barrier();
    __builtin_amdgcn_sched_barrier(0);
    COMPUTE(ksl[1], vtl[1]);
    __builtin_amdgcn_sched_barrier(0);
    asm volatile("" ::: "memory");
    __builtin_amdgcn_s_barrier();

    STAGE(1, t + 4);
    asm volatile("s_waitcnt vmcnt(8)" ::: "memory");
    __builtin_amdgcn_s_barrier();
    __builtin_amdgcn_sched_barrier(0);
    COMPUTE(ksl[2], vtl[2]);
    __builtin_amdgcn_sched_barrier(0);
    asm volatile("" ::: "memory");
    __builtin_amdgcn_s_barrier();
  }
  asm volatile("s_waitcnt vmcnt(4)" ::: "memory");
  __builtin_amdgcn_s_barrier();
  __builtin_amdgcn_sched_barrier(0);
  COMPUTE(ksl[0], vtl[0]);
  __builtin_amdgcn_sched_barrier(0);
  asm volatile("s_waitcnt vmcnt(0)" ::: "memory");
  __builtin_amdgcn_s_barrier();
  __builtin_amdgcn_sched_barrier(0);
  COMPUTE(ksl[1], vtl[1]);

  // ---- fused combine epilogue: xeg[tq][eq*64 + d] = f2bf(gate * o / l) ----
  float lg = l;
  lg += __shfl_xor(lg, 16);
  lg += __shfl_xor(lg, 32);                      // full softmax sum for query nl
  const float scale = gate[tq * Hh + h] / lg;
  unsigned short* xrow = xeg + (size_t)tq * KR + eq * Dd + quad * 4;
  #pragma unroll
  for (int dg = 0; dg < 4; ++dg) {
    ushort4 v;
    v.x = f2bf(acc[dg][0] * scale);
    v.y = f2bf(acc[dg][1] * scale);
    v.z = f2bf(acc[dg][2] * scale);
    v.w = f2bf(acc[dg][3] * scale);
    *(ushort4*)(xrow + dg * 16) = v;
  }
}

// ---------------------------------------------------------------------------
// aux1: parallel bstats row-sum -> stats2[49];  aux2: finalize
// ---------------------------------------------------------------------------
__global__ __launch_bounds__(256) void aux1_kernel(
    const float* __restrict__ bstats, float* __restrict__ stats2)
{
  __shared__ float r[4];
  const int j = blockIdx.x, tid = threadIdx.x;
  float4 v = *(const float4*)&bstats[(size_t)j * NB2 + tid * 4];
  float s = (v.x + v.y) + (v.z + v.w);
  for (int o = 32; o; o >>= 1) s += __shfl_xor(s, o);
  if ((tid & 63) == 0) r[tid >> 6] = s;
  __syncthreads();
  if (tid == 0) stats2[j] = (r[0] + r[1]) + (r[2] + r[3]);
}

__global__ void aux2_kernel(const float* __restrict__ stats2,
                            float* __restrict__ out, int out_size)
{
  const int lane = threadIdx.x;
  float a = (lane < Ee) ? stats2[lane] : 0.f;
  float b = (lane < Ee) ? stats2[24 + lane] : 0.f;
  float pt = a, ft = b, sw = a * b;
  for (int o = 32; o; o >>= 1) {
    pt += __shfl_xor(pt, o); ft += __shfl_xor(ft, o); sw += __shfl_xor(sw, o);
  }
  if (lane == 0) {
    float sswitch = (float)Ee * sw / (pt * ft);
    float z = stats2[48] * (1.0f / (float)T_);
    out[out_size - 1] = 0.1f * sswitch + 0.001f * z;
  }
}

// ---------------------------------------------------------------------------
extern "C" void kernel_launch(void* const* d_in, const int* in_sizes, int n_in,
                              void* d_out, int out_size, void* d_ws, size_t ws_size,
                              hipStream_t stream)
{
  const float* x     = (const float*)d_in[0];
  const float* wg    = (const float*)d_in[1];
  const float* W_in  = (const float*)d_in[2];
  const float* b_in  = (const float*)d_in[3];
  const float* W_out = (const float*)d_in[4];
  const float* b_out = (const float*)d_in[5];
  const float* W_kv  = (const float*)d_in[6];
  const float* b_kv  = (const float*)d_in[7];
  float* out = (float*)d_out;

  char* ws = (char*)d_ws;
  size_t off = 0;
  auto carve = [&](size_t bytes) -> void* {
    void* p = ws + off;
    off = (off + bytes + 255) & ~(size_t)255;
    return p;
  };
  int*            idx    = (int*)           carve((size_t)T_ * Hh * 4);
  float*          gate   = (float*)         carve((size_t)T_ * Hh * 4);
  float*          bstats = (float*)         carve((size_t)49 * NB2 * 4);
  float*          stats2 = (float*)         carve(256);
  float*          lgate  = (float*)         carve((size_t)T_ * KS * Ee * 4);
  unsigned short* xb     = (unsigned short*)carve((size_t)T_ * Cc * 2);
  unsigned short* BqkvT  = (unsigned short*)carve((size_t)(Ee * Dd + 128) * Cc * 2);
  unsigned short* BkvT   = BqkvT + (size_t)Ee * Dd * Cc;
  unsigned short* BrT    = (unsigned short*)carve((size_t)Cc * KR * 2);
  unsigned short* kbuf   = (unsigned short*)carve((size_t)T_ * Dd * 2);
  unsigned short* vtbuf  = (unsigned short*)carve((size_t)T_ * Dd * 2);
  unsigned short* qallb  = (unsigned short*)carve((size_t)T_ * Ee * Dd * 2);
  unsigned short* xeg    = (unsigned short*)carve((size_t)T_ * KR * 2);

  // merged weight conversions (one dispatch)
  convert_all_kernel<<<900, 256, 0, stream>>>(
      W_in, W_out, b_out, W_kv, BqkvT, BrT, BkvT);

  // gating (+ fused x -> bf16); gate2 also zero-fills/preps xeg rows
  gate1_kernel<<<dim3(T_ / 256, KS), 256, 0, stream>>>(x, wg, lgate, xb);
  gate2_kernel<<<NB2, 256, 0, stream>>>(lgate, idx, gate, bstats, xeg);

  // fused qall + kv GEMM: 64x64 tiles, BK=64, grid (64, 26)
  gemm_bt_kernel<1><<<dim3(T_ / 64, 26), 256, 0, stream>>>(
      xb, BqkvT, b_in, b_kv, qallb, kbuf, vtbuf, Cc, 1536);

  // attention with fused combine epilogue -> xeg (scatter eliminated)
  attn_kernel<<<dim3(Nn / 64, Bb * Hh), 256, 0, stream>>>(
      qallb, idx, gate, kbuf, vtbuf, xeg);

  // out = xeg @ BrT^T -> f32: 64x64 tiles, BK=64, grid (64, 12)
  gemm_bt_kernel<0><<<dim3(T_ / 64, Cc / 64), 256, 0, stream>>>(
      xeg, BrT, nullptr, nullptr, out, nullptr, nullptr, KR, Cc);

  // aux loss
  aux1_kernel<<<49, 256, 0, stream>>>(bstats, stats2);
  aux2_kernel<<<1, 64, 0, stream>>>(stats2, out, out_size);
}